// Round 1
// baseline (991.078 us; speedup 1.0000x reference)
//
#include <hip/hip_runtime.h>
#include <math.h>

#define N_NODES 50000
#define E_EDGES 300000
#define E_TOT   350000   // E + N self-loops
#define NEG 0.2f
#define EPS 1e-16f

__device__ __forceinline__ unsigned fenc(float f) {
    unsigned u = __float_as_uint(f);
    return (u & 0x80000000u) ? ~u : (u | 0x80000000u);
}
__device__ __forceinline__ float fdec(unsigned u) {
    return (u & 0x80000000u) ? __uint_as_float(u & 0x7fffffffu)
                             : __uint_as_float(~u);
}
__device__ __forceinline__ float leaky(float x) { return x > 0.f ? x : NEG * x; }

// K1: h1[N,256] = x[N,27] @ W1[27,256]; s1[n][0..3]=src half-scores, [4..7]=dst
__global__ __launch_bounds__(256) void k_gemm1(const float* __restrict__ x,
        const float* __restrict__ W1, const float* __restrict__ as1,
        const float* __restrict__ ad1, float* __restrict__ h1,
        float* __restrict__ s1) {
    __shared__ float W1s[27 * 256];
    __shared__ float xs[16 * 27];
    int t = threadIdx.x;
    for (int i = t; i < 27 * 256; i += 256) W1s[i] = W1[i];
    int base = blockIdx.x * 16;   // 3125 * 16 = 50000 exact
    for (int i = t; i < 16 * 27; i += 256) xs[i] = x[base * 27 + i];
    __syncthreads();
    float asr = as1[t], adt = ad1[t];
    int head = t >> 6;
    for (int j = 0; j < 16; ++j) {
        float acc = 0.f;
        #pragma unroll
        for (int k = 0; k < 27; ++k) acc += xs[j * 27 + k] * W1s[k * 256 + t];
        int n = base + j;
        h1[n * 256 + t] = acc;
        float ps = acc * asr, pd = acc * adt;
        #pragma unroll
        for (int off = 32; off > 0; off >>= 1) {
            ps += __shfl_down(ps, off);
            pd += __shfl_down(pd, off);
        }
        if ((t & 63) == 0) {
            s1[n * 8 + head] = ps;
            s1[n * 8 + 4 + head] = pd;
        }
    }
}

// K2: segment max over dst, 4 heads (ordered-uint encoded, init = 0 = -inf)
__global__ __launch_bounds__(256) void k_max1(const int* __restrict__ ei,
        const float* __restrict__ s1, unsigned* __restrict__ m1) {
    int e = blockIdx.x * 256 + threadIdx.x;
    if (e >= E_TOT) return;
    int s = (e < E_EDGES) ? ei[e] : (e - E_EDGES);
    int d = (e < E_EDGES) ? ei[E_EDGES + e] : (e - E_EDGES);
    const float4 ss = *(const float4*)(s1 + s * 8);
    const float4 sd = *(const float4*)(s1 + d * 8 + 4);
    atomicMax(&m1[d * 4 + 0], fenc(leaky(ss.x + sd.x)));
    atomicMax(&m1[d * 4 + 1], fenc(leaky(ss.y + sd.y)));
    atomicMax(&m1[d * 4 + 2], fenc(leaky(ss.z + sd.z)));
    atomicMax(&m1[d * 4 + 3], fenc(leaky(ss.w + sd.w)));
}

// K3: z[dst][h] += exp(l - m[dst][h])
__global__ __launch_bounds__(256) void k_sum1(const int* __restrict__ ei,
        const float* __restrict__ s1, const unsigned* __restrict__ m1,
        float* __restrict__ z1) {
    int e = blockIdx.x * 256 + threadIdx.x;
    if (e >= E_TOT) return;
    int s = (e < E_EDGES) ? ei[e] : (e - E_EDGES);
    int d = (e < E_EDGES) ? ei[E_EDGES + e] : (e - E_EDGES);
    const float4 ss = *(const float4*)(s1 + s * 8);
    const float4 sd = *(const float4*)(s1 + d * 8 + 4);
    atomicAdd(&z1[d * 4 + 0], __expf(leaky(ss.x + sd.x) - fdec(m1[d * 4 + 0])));
    atomicAdd(&z1[d * 4 + 1], __expf(leaky(ss.y + sd.y) - fdec(m1[d * 4 + 1])));
    atomicAdd(&z1[d * 4 + 2], __expf(leaky(ss.z + sd.z) - fdec(m1[d * 4 + 2])));
    atomicAdd(&z1[d * 4 + 3], __expf(leaky(ss.w + sd.w) - fdec(m1[d * 4 + 3])));
}

// K4: out1[dst][c] += h1[src][c] * alpha   (one block = one edge, 256 channels)
__global__ __launch_bounds__(256) void k_agg1(const int* __restrict__ ei,
        const float* __restrict__ s1, const unsigned* __restrict__ m1,
        const float* __restrict__ z1, const float* __restrict__ h1,
        float* __restrict__ out1) {
    int e = blockIdx.x;
    int t = threadIdx.x;
    int s = (e < E_EDGES) ? ei[e] : (e - E_EDGES);
    int d = (e < E_EDGES) ? ei[E_EDGES + e] : (e - E_EDGES);
    int h = t >> 6;
    float l = leaky(s1[s * 8 + h] + s1[d * 8 + 4 + h]);
    float alpha = __expf(l - fdec(m1[d * 4 + h])) / (z1[d * 4 + h] + EPS);
    atomicAdd(&out1[d * 256 + t], h1[s * 256 + t] * alpha);
}

// K5: out1 = elu(out1 + b1), in place
__global__ __launch_bounds__(256) void k_elu1(float* __restrict__ out1,
        const float* __restrict__ b1) {
    int i = blockIdx.x * 256 + threadIdx.x;   // grid 50000 -> exactly N*256
    float v = out1[i] + b1[i & 255];
    out1[i] = v > 0.f ? v : __expf(v) - 1.f;
}

// K6: h2[N,128] = in[N,256] @ W2[256,128]; s2[n][0..1]=src, [2..3]=dst
__global__ __launch_bounds__(256) void k_gemm2(const float* __restrict__ in,
        const float* __restrict__ W2, const float* __restrict__ as2,
        const float* __restrict__ ad2, float* __restrict__ h2,
        float* __restrict__ s2) {
    __shared__ float ins[8 * 256];
    int t = threadIdx.x;
    int nbase = blockIdx.x * 8;   // 6250 * 8 = 50000 exact
    for (int i = t; i < 8 * 256; i += 256) ins[i] = in[nbase * 256 + i];
    __syncthreads();
    int node = t >> 5;           // 0..7
    int c4 = (t & 31) * 4;       // 0..124
    float4 acc = make_float4(0.f, 0.f, 0.f, 0.f);
    for (int k = 0; k < 256; ++k) {
        float4 w = *(const float4*)(W2 + k * 128 + c4);
        float iv = ins[node * 256 + k];
        acc.x += iv * w.x; acc.y += iv * w.y; acc.z += iv * w.z; acc.w += iv * w.w;
    }
    int n = nbase + node;
    *(float4*)(h2 + n * 128 + c4) = acc;
    float4 a_s = *(const float4*)(as2 + c4);
    float4 a_d = *(const float4*)(ad2 + c4);
    float ps = acc.x * a_s.x + acc.y * a_s.y + acc.z * a_s.z + acc.w * a_s.w;
    float pd = acc.x * a_d.x + acc.y * a_d.y + acc.z * a_d.z + acc.w * a_d.w;
    #pragma unroll
    for (int off = 8; off > 0; off >>= 1) {
        ps += __shfl_down(ps, off);
        pd += __shfl_down(pd, off);
    }
    if ((t & 15) == 0) {
        int head = (t >> 4) & 1;
        s2[n * 4 + head] = ps;
        s2[n * 4 + 2 + head] = pd;
    }
}

__global__ __launch_bounds__(256) void k_max2(const int* __restrict__ ei,
        const float* __restrict__ s2, unsigned* __restrict__ m2) {
    int e = blockIdx.x * 256 + threadIdx.x;
    if (e >= E_TOT) return;
    int s = (e < E_EDGES) ? ei[e] : (e - E_EDGES);
    int d = (e < E_EDGES) ? ei[E_EDGES + e] : (e - E_EDGES);
    const float2 ss = *(const float2*)(s2 + s * 4);
    const float2 sd = *(const float2*)(s2 + d * 4 + 2);
    atomicMax(&m2[d * 2 + 0], fenc(leaky(ss.x + sd.x)));
    atomicMax(&m2[d * 2 + 1], fenc(leaky(ss.y + sd.y)));
}

__global__ __launch_bounds__(256) void k_sum2(const int* __restrict__ ei,
        const float* __restrict__ s2, const unsigned* __restrict__ m2,
        float* __restrict__ z2) {
    int e = blockIdx.x * 256 + threadIdx.x;
    if (e >= E_TOT) return;
    int s = (e < E_EDGES) ? ei[e] : (e - E_EDGES);
    int d = (e < E_EDGES) ? ei[E_EDGES + e] : (e - E_EDGES);
    const float2 ss = *(const float2*)(s2 + s * 4);
    const float2 sd = *(const float2*)(s2 + d * 4 + 2);
    atomicAdd(&z2[d * 2 + 0], __expf(leaky(ss.x + sd.x) - fdec(m2[d * 2 + 0])));
    atomicAdd(&z2[d * 2 + 1], __expf(leaky(ss.y + sd.y) - fdec(m2[d * 2 + 1])));
}

// K9: out2[dst][c] += h2[src][c] * alpha   (block = 2 edges x 128 channels)
__global__ __launch_bounds__(256) void k_agg2(const int* __restrict__ ei,
        const float* __restrict__ s2, const unsigned* __restrict__ m2,
        const float* __restrict__ z2, const float* __restrict__ h2,
        float* __restrict__ out2) {
    int e = blockIdx.x * 2 + (threadIdx.x >> 7);   // grid 175000 -> exact
    int c = threadIdx.x & 127;
    int s = (e < E_EDGES) ? ei[e] : (e - E_EDGES);
    int d = (e < E_EDGES) ? ei[E_EDGES + e] : (e - E_EDGES);
    int h = c >> 6;
    float l = leaky(s2[s * 4 + h] + s2[d * 4 + 2 + h]);
    float alpha = __expf(l - fdec(m2[d * 2 + h])) / (z2[d * 2 + h] + EPS);
    atomicAdd(&out2[d * 128 + c], h2[s * 128 + c] * alpha);
}

// K10: out[n] = sigmoid( elu(out2[n]+b2) . Wfc + bfc )   (one wave per node)
__global__ __launch_bounds__(256) void k_final(const float* __restrict__ out2,
        const float* __restrict__ b2, const float* __restrict__ Wfc,
        const float* __restrict__ bfc, float* __restrict__ out) {
    int n = blockIdx.x * 4 + (threadIdx.x >> 6);
    if (n >= N_NODES) return;
    int l = threadIdx.x & 63;
    float v0 = out2[n * 128 + l] + b2[l];
    v0 = (v0 > 0.f ? v0 : __expf(v0) - 1.f) * Wfc[l];
    float v1 = out2[n * 128 + 64 + l] + b2[64 + l];
    v1 = (v1 > 0.f ? v1 : __expf(v1) - 1.f) * Wfc[64 + l];
    float p = v0 + v1;
    #pragma unroll
    for (int off = 32; off > 0; off >>= 1) p += __shfl_down(p, off);
    if (l == 0) out[n] = 1.f / (1.f + __expf(-(p + bfc[0])));
}

extern "C" void kernel_launch(void* const* d_in, const int* in_sizes, int n_in,
                              void* d_out, int out_size, void* d_ws, size_t ws_size,
                              hipStream_t stream) {
    const float* x   = (const float*)d_in[0];
    const int*   ei  = (const int*)d_in[1];
    const float* W1  = (const float*)d_in[2];
    const float* as1 = (const float*)d_in[3];
    const float* ad1 = (const float*)d_in[4];
    const float* b1  = (const float*)d_in[5];
    const float* W2  = (const float*)d_in[6];
    const float* as2 = (const float*)d_in[7];
    const float* ad2 = (const float*)d_in[8];
    const float* b2  = (const float*)d_in[9];
    const float* Wfc = (const float*)d_in[10];
    const float* bfc = (const float*)d_in[11];
    float* out = (float*)d_out;

    float* f = (float*)d_ws;
    float*    h1   = f;                           // N*256 = 12.8M floats
    float*    out1 = f + 12800000;                // N*256
    float*    s1   = f + 25600000;                // N*8
    unsigned* m1   = (unsigned*)(f + 26000000);   // N*4
    float*    z1   = f + 26200000;                // N*4
    float*    s2   = f + 26400000;                // N*4
    unsigned* m2   = (unsigned*)(f + 26600000);   // N*2
    float*    z2   = f + 26700000;                // N*2
    float*    h2   = h1;                          // alias: N*128, after h1 dead
    float*    out2 = f + 6400000;                 // alias: upper half of h1

    hipMemsetAsync(out1, 0, (size_t)N_NODES * 256 * 4, stream);
    hipMemsetAsync(m1, 0, (size_t)N_NODES * 4 * 4, stream);
    hipMemsetAsync(z1, 0, (size_t)N_NODES * 4 * 4, stream);
    hipMemsetAsync(m2, 0, (size_t)N_NODES * 2 * 4, stream);
    hipMemsetAsync(z2, 0, (size_t)N_NODES * 2 * 4, stream);

    k_gemm1<<<3125, 256, 0, stream>>>(x, W1, as1, ad1, h1, s1);
    k_max1<<<(E_TOT + 255) / 256, 256, 0, stream>>>(ei, s1, m1);
    k_sum1<<<(E_TOT + 255) / 256, 256, 0, stream>>>(ei, s1, m1, z1);
    k_agg1<<<E_TOT, 256, 0, stream>>>(ei, s1, m1, z1, h1, out1);
    k_elu1<<<50000, 256, 0, stream>>>(out1, b1);
    hipMemsetAsync(out2, 0, (size_t)N_NODES * 128 * 4, stream);
    k_gemm2<<<6250, 256, 0, stream>>>(out1, W2, as2, ad2, h2, s2);
    k_max2<<<(E_TOT + 255) / 256, 256, 0, stream>>>(ei, s2, m2);
    k_sum2<<<(E_TOT + 255) / 256, 256, 0, stream>>>(ei, s2, m2, z2);
    k_agg2<<<E_TOT / 2, 256, 0, stream>>>(ei, s2, m2, z2, h2, out2);
    k_final<<<12500, 256, 0, stream>>>(out2, b2, Wfc, bfc, out);
}

// Round 2
// 662.752 us; speedup vs baseline: 1.4954x; 1.4954x over previous
//
#include <hip/hip_runtime.h>
#include <math.h>

#define N_NODES 50000
#define E_EDGES 300000
#define E_TOT   350000   // E + N self-loops
#define NEG 0.2f
#define EPS 1e-16f

__device__ __forceinline__ float leaky(float x) { return x > 0.f ? x : NEG * x; }

// ---------------- CSR construction ----------------

__global__ __launch_bounds__(256) void k_hist(const int* __restrict__ ei,
        int* __restrict__ deg) {
    int e = blockIdx.x * 256 + threadIdx.x;
    if (e >= E_TOT) return;
    int d = (e < E_EDGES) ? ei[E_EDGES + e] : (e - E_EDGES);
    atomicAdd(&deg[d], 1);
}

// single-block exclusive scan of deg[0..N) -> rowptr, cursor  (256 thr x 196)
__global__ __launch_bounds__(256) void k_scan(const int* __restrict__ deg,
        int* __restrict__ rowptr, int* __restrict__ cursor) {
    __shared__ int part[256];
    int t = threadIdx.x;
    const int CH = 196;            // 256*196 = 50176 >= 50000
    int base = t * CH;
    int sum = 0;
    for (int i = 0; i < CH; ++i) {
        int idx = base + i;
        if (idx < N_NODES) sum += deg[idx];
    }
    part[t] = sum;
    __syncthreads();
    for (int s = 1; s < 256; s <<= 1) {
        int v = (t >= s) ? part[t - s] : 0;
        __syncthreads();
        part[t] += v;
        __syncthreads();
    }
    int off = (t == 0) ? 0 : part[t - 1];
    for (int i = 0; i < CH; ++i) {
        int idx = base + i;
        if (idx < N_NODES) {
            rowptr[idx] = off;
            cursor[idx] = off;
            off += deg[idx];
        }
    }
    if (t == 255) rowptr[N_NODES] = E_TOT;
}

__global__ __launch_bounds__(256) void k_scatter(const int* __restrict__ ei,
        int* __restrict__ cursor, int* __restrict__ eidx) {
    int e = blockIdx.x * 256 + threadIdx.x;
    if (e >= E_TOT) return;
    int s = (e < E_EDGES) ? ei[e] : (e - E_EDGES);
    int d = (e < E_EDGES) ? ei[E_EDGES + e] : (e - E_EDGES);
    int pos = atomicAdd(&cursor[d], 1);
    eidx[pos] = s;
}

// ---------------- layer computations ----------------

// K1: h1[N,256] = x[N,27] @ W1[27,256]; s1[n][0..3]=src half-scores, [4..7]=dst
__global__ __launch_bounds__(256) void k_gemm1(const float* __restrict__ x,
        const float* __restrict__ W1, const float* __restrict__ as1,
        const float* __restrict__ ad1, float* __restrict__ h1,
        float* __restrict__ s1) {
    __shared__ float W1s[27 * 256];
    __shared__ float xs[16 * 27];
    int t = threadIdx.x;
    for (int i = t; i < 27 * 256; i += 256) W1s[i] = W1[i];
    int base = blockIdx.x * 16;   // 3125 * 16 = 50000 exact
    for (int i = t; i < 16 * 27; i += 256) xs[i] = x[base * 27 + i];
    __syncthreads();
    float asr = as1[t], adt = ad1[t];
    int head = t >> 6;
    for (int j = 0; j < 16; ++j) {
        float acc = 0.f;
        #pragma unroll
        for (int k = 0; k < 27; ++k) acc += xs[j * 27 + k] * W1s[k * 256 + t];
        int n = base + j;
        h1[n * 256 + t] = acc;
        float ps = acc * asr, pd = acc * adt;
        #pragma unroll
        for (int off = 32; off > 0; off >>= 1) {
            ps += __shfl_down(ps, off);
            pd += __shfl_down(pd, off);
        }
        if ((t & 63) == 0) {
            s1[n * 8 + head] = ps;
            s1[n * 8 + 4 + head] = pd;
        }
    }
}

// Fused layer-1: per-node softmax stats (regs) + gather-aggregate + bias + ELU.
// Block 256 = one dst node; channels = threads; 4 heads of 64.
__global__ __launch_bounds__(256) void k_agg1_csr(const int* __restrict__ rowptr,
        const int* __restrict__ eidx, const float* __restrict__ s1,
        const float* __restrict__ h1, const float* __restrict__ b1,
        float* __restrict__ out1) {
    int n = blockIdx.x;
    int t = threadIdx.x;
    int beg = rowptr[n];
    int deg = rowptr[n + 1] - beg;
    __shared__ float mz[8];        // m[0..3], z[4..7]
    __shared__ int   srcs_sh[64];
    __shared__ float alpha_sh[64 * 4];
    // phase 1: per-head max & expsum, computed by wave 0
    if (t < 64) {
        int h = t & 3, slot = t >> 2;     // 16 slots per head
        float sd = s1[n * 8 + 4 + h];
        float mloc = -1e30f;
        for (int i = slot; i < deg; i += 16)
            mloc = fmaxf(mloc, leaky(s1[eidx[beg + i] * 8 + h] + sd));
        #pragma unroll
        for (int off = 4; off <= 32; off <<= 1)
            mloc = fmaxf(mloc, __shfl_xor(mloc, off));
        float zloc = 0.f;
        for (int i = slot; i < deg; i += 16)
            zloc += __expf(leaky(s1[eidx[beg + i] * 8 + h] + sd) - mloc);
        #pragma unroll
        for (int off = 4; off <= 32; off <<= 1)
            zloc += __shfl_xor(zloc, off);
        if (slot == 0) { mz[h] = mloc; mz[4 + h] = zloc; }
    }
    __syncthreads();
    // phase 2: chunked alpha + gather-accumulate
    float acc = 0.f;
    int h = t >> 6;
    for (int c0 = 0; c0 < deg; c0 += 64) {
        int cnt = min(64, deg - c0);
        int i = t >> 2, hh = t & 3;
        if (i < cnt) {
            int src = eidx[beg + c0 + i];
            if (hh == 0) srcs_sh[i] = src;
            float l = leaky(s1[src * 8 + hh] + s1[n * 8 + 4 + hh]);
            alpha_sh[i * 4 + hh] = __expf(l - mz[hh]) / (mz[4 + hh] + EPS);
        }
        __syncthreads();
        for (int i2 = 0; i2 < cnt; ++i2)
            acc += h1[srcs_sh[i2] * 256 + t] * alpha_sh[i2 * 4 + h];
        __syncthreads();
    }
    float v = acc + b1[t];
    out1[n * 256 + t] = v > 0.f ? v : __expf(v) - 1.f;
}

// K6: h2[N,128] = in[N,256] @ W2[256,128]; s2[n][0..1]=src, [2..3]=dst
__global__ __launch_bounds__(256) void k_gemm2(const float* __restrict__ in,
        const float* __restrict__ W2, const float* __restrict__ as2,
        const float* __restrict__ ad2, float* __restrict__ h2,
        float* __restrict__ s2) {
    __shared__ float ins[8 * 256];
    int t = threadIdx.x;
    int nbase = blockIdx.x * 8;   // 6250 * 8 = 50000 exact
    for (int i = t; i < 8 * 256; i += 256) ins[i] = in[nbase * 256 + i];
    __syncthreads();
    int node = t >> 5;           // 0..7
    int c4 = (t & 31) * 4;       // 0..124
    float4 acc = make_float4(0.f, 0.f, 0.f, 0.f);
    for (int k = 0; k < 256; ++k) {
        float4 w = *(const float4*)(W2 + k * 128 + c4);
        float iv = ins[node * 256 + k];
        acc.x += iv * w.x; acc.y += iv * w.y; acc.z += iv * w.z; acc.w += iv * w.w;
    }
    int n = nbase + node;
    *(float4*)(h2 + n * 128 + c4) = acc;
    float4 a_s = *(const float4*)(as2 + c4);
    float4 a_d = *(const float4*)(ad2 + c4);
    float ps = acc.x * a_s.x + acc.y * a_s.y + acc.z * a_s.z + acc.w * a_s.w;
    float pd = acc.x * a_d.x + acc.y * a_d.y + acc.z * a_d.z + acc.w * a_d.w;
    #pragma unroll
    for (int off = 8; off > 0; off >>= 1) {
        ps += __shfl_down(ps, off);
        pd += __shfl_down(pd, off);
    }
    if ((t & 15) == 0) {
        int head = (t >> 4) & 1;
        s2[n * 4 + head] = ps;
        s2[n * 4 + 2 + head] = pd;
    }
}

// Fused layer-2: softmax stats + gather-aggregate + bias + ELU + FC + sigmoid.
// Block 128 = one dst node; 2 heads of 64 channels. Writes out[n] directly.
__global__ __launch_bounds__(128) void k_agg2_csr(const int* __restrict__ rowptr,
        const int* __restrict__ eidx, const float* __restrict__ s2,
        const float* __restrict__ h2, const float* __restrict__ b2,
        const float* __restrict__ Wfc, const float* __restrict__ bfc,
        float* __restrict__ out) {
    int n = blockIdx.x;
    int t = threadIdx.x;
    int beg = rowptr[n];
    int deg = rowptr[n + 1] - beg;
    __shared__ float mz[4];        // m[0..1], z[2..3]
    __shared__ int   srcs_sh[64];
    __shared__ float alpha_sh[64 * 2];
    __shared__ float red[2];
    if (t < 64) {
        int h = t & 1, slot = t >> 1;    // 32 slots per head
        float sd = s2[n * 4 + 2 + h];
        float mloc = -1e30f;
        for (int i = slot; i < deg; i += 32)
            mloc = fmaxf(mloc, leaky(s2[eidx[beg + i] * 4 + h] + sd));
        #pragma unroll
        for (int off = 2; off <= 32; off <<= 1)
            mloc = fmaxf(mloc, __shfl_xor(mloc, off));
        float zloc = 0.f;
        for (int i = slot; i < deg; i += 32)
            zloc += __expf(leaky(s2[eidx[beg + i] * 4 + h] + sd) - mloc);
        #pragma unroll
        for (int off = 2; off <= 32; off <<= 1)
            zloc += __shfl_xor(zloc, off);
        if (slot == 0) { mz[h] = mloc; mz[2 + h] = zloc; }
    }
    __syncthreads();
    float acc = 0.f;
    int h = t >> 6;
    for (int c0 = 0; c0 < deg; c0 += 64) {
        int cnt = min(64, deg - c0);
        int i = t >> 1, hh = t & 1;
        if (i < cnt) {
            int src = eidx[beg + c0 + i];
            if (hh == 0) srcs_sh[i] = src;
            float l = leaky(s2[src * 4 + hh] + s2[n * 4 + 2 + hh]);
            alpha_sh[i * 2 + hh] = __expf(l - mz[hh]) / (mz[2 + hh] + EPS);
        }
        __syncthreads();
        for (int i2 = 0; i2 < cnt; ++i2)
            acc += h2[srcs_sh[i2] * 128 + t] * alpha_sh[i2 * 2 + h];
        __syncthreads();
    }
    // epilogue: elu(acc+b2) . Wfc -> sigmoid
    float v = acc + b2[t];
    v = v > 0.f ? v : __expf(v) - 1.f;
    float p = v * Wfc[t];
    #pragma unroll
    for (int off = 32; off > 0; off >>= 1) p += __shfl_down(p, off);
    if ((t & 63) == 0) red[t >> 6] = p;
    __syncthreads();
    if (t == 0) out[n] = 1.f / (1.f + __expf(-(red[0] + red[1] + bfc[0])));
}

extern "C" void kernel_launch(void* const* d_in, const int* in_sizes, int n_in,
                              void* d_out, int out_size, void* d_ws, size_t ws_size,
                              hipStream_t stream) {
    const float* x   = (const float*)d_in[0];
    const int*   ei  = (const int*)d_in[1];
    const float* W1  = (const float*)d_in[2];
    const float* as1 = (const float*)d_in[3];
    const float* ad1 = (const float*)d_in[4];
    const float* b1  = (const float*)d_in[5];
    const float* W2  = (const float*)d_in[6];
    const float* as2 = (const float*)d_in[7];
    const float* ad2 = (const float*)d_in[8];
    const float* b2  = (const float*)d_in[9];
    const float* Wfc = (const float*)d_in[10];
    const float* bfc = (const float*)d_in[11];
    float* out = (float*)d_out;

    float* f = (float*)d_ws;
    float* h1     = f;                         // N*256
    float* out1   = f + 12800000;              // N*256
    float* s1     = f + 25600000;              // N*8
    float* s2     = f + 26000000;              // N*4
    int*   rowptr = (int*)(f + 26200000);      // N+1
    int*   cursor = (int*)(f + 26260000);      // N
    int*   deg    = (int*)(f + 26320000);      // N
    int*   eidx   = (int*)(f + 26380000);      // E_TOT
    float* h2     = h1;                        // alias: N*128 (h1 dead by then)

    // CSR build
    hipMemsetAsync(deg, 0, (size_t)N_NODES * 4, stream);
    k_hist<<<(E_TOT + 255) / 256, 256, 0, stream>>>(ei, deg);
    k_scan<<<1, 256, 0, stream>>>(deg, rowptr, cursor);
    k_scatter<<<(E_TOT + 255) / 256, 256, 0, stream>>>(ei, cursor, eidx);

    // layer 1
    k_gemm1<<<3125, 256, 0, stream>>>(x, W1, as1, ad1, h1, s1);
    k_agg1_csr<<<N_NODES, 256, 0, stream>>>(rowptr, eidx, s1, h1, b1, out1);

    // layer 2 (+ final FC + sigmoid fused)
    k_gemm2<<<6250, 256, 0, stream>>>(out1, W2, as2, ad2, h2, s2);
    k_agg2_csr<<<N_NODES, 128, 0, stream>>>(rowptr, eidx, s2, h2, b2, Wfc, bfc, out);
}

// Round 3
// 558.585 us; speedup vs baseline: 1.7743x; 1.1865x over previous
//
#include <hip/hip_runtime.h>
#include <math.h>

#define N_NODES 50000
#define E_EDGES 300000
#define E_TOT   350000   // E + N self-loops
#define NEG 0.2f
#define EPS 1e-16f

__device__ __forceinline__ float leaky(float x) { return x > 0.f ? x : NEG * x; }

// ---------------- CSR construction ----------------

__global__ __launch_bounds__(256) void k_hist(const int* __restrict__ ei,
        int* __restrict__ deg) {
    int e = blockIdx.x * 256 + threadIdx.x;
    if (e >= E_TOT) return;
    int d = (e < E_EDGES) ? ei[E_EDGES + e] : (e - E_EDGES);
    atomicAdd(&deg[d], 1);
}

__global__ __launch_bounds__(256) void k_scan(const int* __restrict__ deg,
        int* __restrict__ rowptr, int* __restrict__ cursor) {
    __shared__ int part[256];
    int t = threadIdx.x;
    const int CH = 196;            // 256*196 = 50176 >= 50000
    int base = t * CH;
    int sum = 0;
    for (int i = 0; i < CH; ++i) {
        int idx = base + i;
        if (idx < N_NODES) sum += deg[idx];
    }
    part[t] = sum;
    __syncthreads();
    for (int s = 1; s < 256; s <<= 1) {
        int v = (t >= s) ? part[t - s] : 0;
        __syncthreads();
        part[t] += v;
        __syncthreads();
    }
    int off = (t == 0) ? 0 : part[t - 1];
    for (int i = 0; i < CH; ++i) {
        int idx = base + i;
        if (idx < N_NODES) {
            rowptr[idx] = off;
            cursor[idx] = off;
            off += deg[idx];
        }
    }
    if (t == 255) rowptr[N_NODES] = E_TOT;
}

__global__ __launch_bounds__(256) void k_scatter(const int* __restrict__ ei,
        int* __restrict__ cursor, int* __restrict__ eidx) {
    int e = blockIdx.x * 256 + threadIdx.x;
    if (e >= E_TOT) return;
    int s = (e < E_EDGES) ? ei[e] : (e - E_EDGES);
    int d = (e < E_EDGES) ? ei[E_EDGES + e] : (e - E_EDGES);
    int pos = atomicAdd(&cursor[d], 1);
    eidx[pos] = s;
}

// ---------------- layer computations ----------------

// K1: h1[N,256] = x[N,27] @ W1[27,256]; s1[n][0..3]=src half-scores, [4..7]=dst
__global__ __launch_bounds__(256) void k_gemm1(const float* __restrict__ x,
        const float* __restrict__ W1, const float* __restrict__ as1,
        const float* __restrict__ ad1, float* __restrict__ h1,
        float* __restrict__ s1) {
    __shared__ float W1s[27 * 256];
    __shared__ float xs[16 * 27];
    int t = threadIdx.x;
    for (int i = t; i < 27 * 256; i += 256) W1s[i] = W1[i];
    int base = blockIdx.x * 16;   // 3125 * 16 = 50000 exact
    for (int i = t; i < 16 * 27; i += 256) xs[i] = x[base * 27 + i];
    __syncthreads();
    float asr = as1[t], adt = ad1[t];
    int head = t >> 6;
    for (int j = 0; j < 16; ++j) {
        float acc = 0.f;
        #pragma unroll
        for (int k = 0; k < 27; ++k) acc += xs[j * 27 + k] * W1s[k * 256 + t];
        int n = base + j;
        h1[n * 256 + t] = acc;
        float ps = acc * asr, pd = acc * adt;
        #pragma unroll
        for (int off = 32; off > 0; off >>= 1) {
            ps += __shfl_down(ps, off);
            pd += __shfl_down(pd, off);
        }
        if ((t & 63) == 0) {
            s1[n * 8 + head] = ps;
            s1[n * 8 + 4 + head] = pd;
        }
    }
}

// Fused layer-1: per-node softmax stats (regs) + gather-aggregate + bias + ELU.
__global__ __launch_bounds__(256) void k_agg1_csr(const int* __restrict__ rowptr,
        const int* __restrict__ eidx, const float* __restrict__ s1,
        const float* __restrict__ h1, const float* __restrict__ b1,
        float* __restrict__ out1) {
    int n = blockIdx.x;
    int t = threadIdx.x;
    int beg = rowptr[n];
    int deg = rowptr[n + 1] - beg;
    __shared__ float mz[8];        // m[0..3], z[4..7]
    __shared__ int   srcs_sh[64];
    __shared__ float alpha_sh[64 * 4];
    if (t < 64) {
        int h = t & 3, slot = t >> 2;     // 16 slots per head
        float sd = s1[n * 8 + 4 + h];
        float mloc = -1e30f;
        for (int i = slot; i < deg; i += 16)
            mloc = fmaxf(mloc, leaky(s1[eidx[beg + i] * 8 + h] + sd));
        #pragma unroll
        for (int off = 4; off <= 32; off <<= 1)
            mloc = fmaxf(mloc, __shfl_xor(mloc, off));
        float zloc = 0.f;
        for (int i = slot; i < deg; i += 16)
            zloc += __expf(leaky(s1[eidx[beg + i] * 8 + h] + sd) - mloc);
        #pragma unroll
        for (int off = 4; off <= 32; off <<= 1)
            zloc += __shfl_xor(zloc, off);
        if (slot == 0) { mz[h] = mloc; mz[4 + h] = zloc; }
    }
    __syncthreads();
    float acc = 0.f;
    int h = t >> 6;
    for (int c0 = 0; c0 < deg; c0 += 64) {
        int cnt = min(64, deg - c0);
        int i = t >> 2, hh = t & 3;
        if (i < cnt) {
            int src = eidx[beg + c0 + i];
            if (hh == 0) srcs_sh[i] = src;
            float l = leaky(s1[src * 8 + hh] + s1[n * 8 + 4 + hh]);
            alpha_sh[i * 4 + hh] = __expf(l - mz[hh]) / (mz[4 + hh] + EPS);
        }
        __syncthreads();
        for (int i2 = 0; i2 < cnt; ++i2)
            acc += h1[srcs_sh[i2] * 256 + t] * alpha_sh[i2 * 4 + h];
        __syncthreads();
    }
    float v = acc + b1[t];
    out1[n * 256 + t] = v > 0.f ? v : __expf(v) - 1.f;
}

// K6: h2[N,128] = in[N,256] @ W2[256,128] — LDS-tiled, register-blocked.
// Block: 64 rows x 128 cols, KC=32. Thread tile: 4 rows x 8 cols.
// Also emits s2[n][0..1]=src half-scores, [2..3]=dst via shfl reduction.
__global__ __launch_bounds__(256) void k_gemm2(const float* __restrict__ in,
        const float* __restrict__ W2, const float* __restrict__ as2,
        const float* __restrict__ ad2, float* __restrict__ h2,
        float* __restrict__ s2) {
    __shared__ float As[32][68];   // A^T chunk [k][row], row stride 68 (16B-aligned)
    __shared__ float Bs[32][128];  // B chunk [k][col]
    int t = threadIdx.x;
    int n0 = blockIdx.x * 64;      // grid 782; last block partial (50000=781*64+16)
    int rg = t >> 4;               // 0..15 -> rows rg*4 .. rg*4+3
    int cg = t & 15;               // 0..15 -> cols cg*8 .. cg*8+7
    float acc[4][8];
    #pragma unroll
    for (int r = 0; r < 4; ++r)
        #pragma unroll
        for (int c = 0; c < 8; ++c) acc[r][c] = 0.f;

    for (int k0 = 0; k0 < 256; k0 += 32) {
        // stage A chunk (transposed): 64 rows x 32 k
        {
            int c = t & 31;        // k within chunk
            int r0 = t >> 5;       // 0..7
            #pragma unroll
            for (int i = 0; i < 8; ++i) {
                int r = r0 + i * 8;
                int n = n0 + r;
                As[c][r] = (n < N_NODES) ? in[n * 256 + k0 + c] : 0.f;
            }
        }
        // stage B chunk: 32 k x 128 cols
        #pragma unroll
        for (int i = 0; i < 16; ++i) {
            int idx = i * 256 + t;
            int kk = idx >> 7, c = idx & 127;
            Bs[kk][c] = W2[(k0 + kk) * 128 + c];
        }
        __syncthreads();
        #pragma unroll 8
        for (int kk = 0; kk < 32; ++kk) {
            float4 a = *(const float4*)&As[kk][rg * 4];
            float4 b0 = *(const float4*)&Bs[kk][cg * 8];
            float4 b1v = *(const float4*)&Bs[kk][cg * 8 + 4];
            float av[4] = {a.x, a.y, a.z, a.w};
            float bv[8] = {b0.x, b0.y, b0.z, b0.w, b1v.x, b1v.y, b1v.z, b1v.w};
            #pragma unroll
            for (int r = 0; r < 4; ++r)
                #pragma unroll
                for (int c = 0; c < 8; ++c)
                    acc[r][c] += av[r] * bv[c];
        }
        __syncthreads();
    }
    // epilogue: store h2 rows + s2 half-scores
    float ps[4], pd[4];
    #pragma unroll
    for (int r = 0; r < 4; ++r) { ps[r] = 0.f; pd[r] = 0.f; }
    #pragma unroll
    for (int c = 0; c < 8; ++c) {
        float a_s = as2[cg * 8 + c];
        float a_d = ad2[cg * 8 + c];
        #pragma unroll
        for (int r = 0; r < 4; ++r) {
            ps[r] += acc[r][c] * a_s;
            pd[r] += acc[r][c] * a_d;
        }
    }
    #pragma unroll
    for (int r = 0; r < 4; ++r) {
        int n = n0 + rg * 4 + r;
        if (n < N_NODES) {
            float4 o0 = make_float4(acc[r][0], acc[r][1], acc[r][2], acc[r][3]);
            float4 o1 = make_float4(acc[r][4], acc[r][5], acc[r][6], acc[r][7]);
            *(float4*)(h2 + n * 128 + cg * 8) = o0;
            *(float4*)(h2 + n * 128 + cg * 8 + 4) = o1;
        }
    }
    #pragma unroll
    for (int off = 1; off <= 4; off <<= 1) {
        #pragma unroll
        for (int r = 0; r < 4; ++r) {
            ps[r] += __shfl_xor(ps[r], off);
            pd[r] += __shfl_xor(pd[r], off);
        }
    }
    if ((cg & 7) == 0) {
        int head = cg >> 3;
        #pragma unroll
        for (int r = 0; r < 4; ++r) {
            int n = n0 + rg * 4 + r;
            if (n < N_NODES) {
                s2[n * 4 + head] = ps[r];
                s2[n * 4 + 2 + head] = pd[r];
            }
        }
    }
}

// Fused layer-2: softmax stats + gather-aggregate + bias + ELU + FC + sigmoid.
__global__ __launch_bounds__(128) void k_agg2_csr(const int* __restrict__ rowptr,
        const int* __restrict__ eidx, const float* __restrict__ s2,
        const float* __restrict__ h2, const float* __restrict__ b2,
        const float* __restrict__ Wfc, const float* __restrict__ bfc,
        float* __restrict__ out) {
    int n = blockIdx.x;
    int t = threadIdx.x;
    int beg = rowptr[n];
    int deg = rowptr[n + 1] - beg;
    __shared__ float mz[4];        // m[0..1], z[2..3]
    __shared__ int   srcs_sh[64];
    __shared__ float alpha_sh[64 * 2];
    __shared__ float red[2];
    if (t < 64) {
        int h = t & 1, slot = t >> 1;    // 32 slots per head
        float sd = s2[n * 4 + 2 + h];
        float mloc = -1e30f;
        for (int i = slot; i < deg; i += 32)
            mloc = fmaxf(mloc, leaky(s2[eidx[beg + i] * 4 + h] + sd));
        #pragma unroll
        for (int off = 2; off <= 32; off <<= 1)
            mloc = fmaxf(mloc, __shfl_xor(mloc, off));
        float zloc = 0.f;
        for (int i = slot; i < deg; i += 32)
            zloc += __expf(leaky(s2[eidx[beg + i] * 4 + h] + sd) - mloc);
        #pragma unroll
        for (int off = 2; off <= 32; off <<= 1)
            zloc += __shfl_xor(zloc, off);
        if (slot == 0) { mz[h] = mloc; mz[2 + h] = zloc; }
    }
    __syncthreads();
    float acc = 0.f;
    int h = t >> 6;
    for (int c0 = 0; c0 < deg; c0 += 64) {
        int cnt = min(64, deg - c0);
        int i = t >> 1, hh = t & 1;
        if (i < cnt) {
            int src = eidx[beg + c0 + i];
            if (hh == 0) srcs_sh[i] = src;
            float l = leaky(s2[src * 4 + hh] + s2[n * 4 + 2 + hh]);
            alpha_sh[i * 2 + hh] = __expf(l - mz[hh]) / (mz[2 + hh] + EPS);
        }
        __syncthreads();
        for (int i2 = 0; i2 < cnt; ++i2)
            acc += h2[srcs_sh[i2] * 128 + t] * alpha_sh[i2 * 2 + h];
        __syncthreads();
    }
    float v = acc + b2[t];
    v = v > 0.f ? v : __expf(v) - 1.f;
    float p = v * Wfc[t];
    #pragma unroll
    for (int off = 32; off > 0; off >>= 1) p += __shfl_down(p, off);
    if ((t & 63) == 0) red[t >> 6] = p;
    __syncthreads();
    if (t == 0) out[n] = 1.f / (1.f + __expf(-(red[0] + red[1] + bfc[0])));
}

extern "C" void kernel_launch(void* const* d_in, const int* in_sizes, int n_in,
                              void* d_out, int out_size, void* d_ws, size_t ws_size,
                              hipStream_t stream) {
    const float* x   = (const float*)d_in[0];
    const int*   ei  = (const int*)d_in[1];
    const float* W1  = (const float*)d_in[2];
    const float* as1 = (const float*)d_in[3];
    const float* ad1 = (const float*)d_in[4];
    const float* b1  = (const float*)d_in[5];
    const float* W2  = (const float*)d_in[6];
    const float* as2 = (const float*)d_in[7];
    const float* ad2 = (const float*)d_in[8];
    const float* b2  = (const float*)d_in[9];
    const float* Wfc = (const float*)d_in[10];
    const float* bfc = (const float*)d_in[11];
    float* out = (float*)d_out;

    float* f = (float*)d_ws;
    float* h1     = f;                         // N*256
    float* out1   = f + 12800000;              // N*256
    float* s1     = f + 25600000;              // N*8
    float* s2     = f + 26000000;              // N*4
    int*   rowptr = (int*)(f + 26200000);      // N+1
    int*   cursor = (int*)(f + 26260000);      // N
    int*   deg    = (int*)(f + 26320000);      // N
    int*   eidx   = (int*)(f + 26380000);      // E_TOT
    float* h2     = h1;                        // alias: N*128 (h1 dead by then)

    // CSR build
    hipMemsetAsync(deg, 0, (size_t)N_NODES * 4, stream);
    k_hist<<<(E_TOT + 255) / 256, 256, 0, stream>>>(ei, deg);
    k_scan<<<1, 256, 0, stream>>>(deg, rowptr, cursor);
    k_scatter<<<(E_TOT + 255) / 256, 256, 0, stream>>>(ei, cursor, eidx);

    // layer 1
    k_gemm1<<<3125, 256, 0, stream>>>(x, W1, as1, ad1, h1, s1);
    k_agg1_csr<<<N_NODES, 256, 0, stream>>>(rowptr, eidx, s1, h1, b1, out1);

    // layer 2 (+ final FC + sigmoid fused)
    k_gemm2<<<(N_NODES + 63) / 64, 256, 0, stream>>>(out1, W2, as2, ad2, h2, s2);
    k_agg2_csr<<<N_NODES, 128, 0, stream>>>(rowptr, eidx, s2, h2, b2, Wfc, bfc, out);
}

// Round 4
// 433.191 us; speedup vs baseline: 2.2879x; 1.2895x over previous
//
#include <hip/hip_runtime.h>
#include <math.h>

#define N_NODES 50000
#define E_EDGES 300000
#define E_TOT   350000   // E + N self-loops
#define NEG 0.2f
#define EPS 1e-16f
#define SCAN_BLOCKS 196  // 196*256 = 50176 >= 50000

__device__ __forceinline__ float leaky(float x) { return x > 0.f ? x : NEG * x; }

// ---------------- CSR construction ----------------

__global__ __launch_bounds__(256) void k_hist(const int* __restrict__ ei,
        int* __restrict__ deg) {
    int e = blockIdx.x * 256 + threadIdx.x;
    if (e >= E_TOT) return;
    int d = (e < E_EDGES) ? ei[E_EDGES + e] : (e - E_EDGES);
    atomicAdd(&deg[d], 1);
}

// stage 1: per-block (256-elem) sums of deg
__global__ __launch_bounds__(256) void k_blocksum(const int* __restrict__ deg,
        int* __restrict__ bsum) {
    int t = threadIdx.x;
    int idx = blockIdx.x * 256 + t;
    int v = (idx < N_NODES) ? deg[idx] : 0;
    #pragma unroll
    for (int off = 32; off > 0; off >>= 1) v += __shfl_down(v, off);
    __shared__ int ws[4];
    if ((t & 63) == 0) ws[t >> 6] = v;
    __syncthreads();
    if (t == 0) bsum[blockIdx.x] = ws[0] + ws[1] + ws[2] + ws[3];
}

// stage 2: single-block exclusive scan of the 196 block sums
__global__ __launch_bounds__(256) void k_scanb(const int* __restrict__ bsum,
        int* __restrict__ bofs) {
    __shared__ int sh[256];
    int t = threadIdx.x;
    sh[t] = (t < SCAN_BLOCKS) ? bsum[t] : 0;
    __syncthreads();
    for (int s = 1; s < 256; s <<= 1) {
        int v = (t >= s) ? sh[t - s] : 0;
        __syncthreads();
        sh[t] += v;
        __syncthreads();
    }
    bofs[t] = (t == 0) ? 0 : sh[t - 1];
}

// stage 3: block-local scan + global offset -> rowptr, cursor
__global__ __launch_bounds__(256) void k_rowptr(const int* __restrict__ deg,
        const int* __restrict__ bofs, int* __restrict__ rowptr,
        int* __restrict__ cursor) {
    __shared__ int sh[256];
    int t = threadIdx.x;
    int idx = blockIdx.x * 256 + t;
    int v = (idx < N_NODES) ? deg[idx] : 0;
    sh[t] = v;
    __syncthreads();
    for (int s = 1; s < 256; s <<= 1) {
        int u = (t >= s) ? sh[t - s] : 0;
        __syncthreads();
        sh[t] += u;
        __syncthreads();
    }
    int excl = sh[t] - v + bofs[blockIdx.x];
    if (idx < N_NODES) { rowptr[idx] = excl; cursor[idx] = excl; }
    if (idx == N_NODES) rowptr[N_NODES] = E_TOT;
}

__global__ __launch_bounds__(256) void k_scatter(const int* __restrict__ ei,
        int* __restrict__ cursor, int* __restrict__ eidx) {
    int e = blockIdx.x * 256 + threadIdx.x;
    if (e >= E_TOT) return;
    int s = (e < E_EDGES) ? ei[e] : (e - E_EDGES);
    int d = (e < E_EDGES) ? ei[E_EDGES + e] : (e - E_EDGES);
    int pos = atomicAdd(&cursor[d], 1);
    eidx[pos] = s;
}

// ---------------- layer computations ----------------

// K1: h1[N,256] = x[N,27] @ W1[27,256]; s1[n][0..3]=src half-scores, [4..7]=dst
__global__ __launch_bounds__(256) void k_gemm1(const float* __restrict__ x,
        const float* __restrict__ W1, const float* __restrict__ as1,
        const float* __restrict__ ad1, float* __restrict__ h1,
        float* __restrict__ s1) {
    __shared__ float W1s[27 * 256];
    __shared__ float xs[16 * 27];
    int t = threadIdx.x;
    for (int i = t; i < 27 * 256; i += 256) W1s[i] = W1[i];
    int base = blockIdx.x * 16;   // 3125 * 16 = 50000 exact
    for (int i = t; i < 16 * 27; i += 256) xs[i] = x[base * 27 + i];
    __syncthreads();
    float asr = as1[t], adt = ad1[t];
    int head = t >> 6;
    for (int j = 0; j < 16; ++j) {
        float acc = 0.f;
        #pragma unroll
        for (int k = 0; k < 27; ++k) acc += xs[j * 27 + k] * W1s[k * 256 + t];
        int n = base + j;
        h1[n * 256 + t] = acc;
        float ps = acc * asr, pd = acc * adt;
        #pragma unroll
        for (int off = 32; off > 0; off >>= 1) {
            ps += __shfl_down(ps, off);
            pd += __shfl_down(pd, off);
        }
        if ((t & 63) == 0) {
            s1[n * 8 + head] = ps;
            s1[n * 8 + 4 + head] = pd;
        }
    }
}

// Fused layer-1: per-node softmax stats (regs) + gather-aggregate + bias + ELU.
__global__ __launch_bounds__(256) void k_agg1_csr(const int* __restrict__ rowptr,
        const int* __restrict__ eidx, const float* __restrict__ s1,
        const float* __restrict__ h1, const float* __restrict__ b1,
        float* __restrict__ out1) {
    int n = blockIdx.x;
    int t = threadIdx.x;
    int beg = rowptr[n];
    int deg = rowptr[n + 1] - beg;
    __shared__ float mz[8];        // m[0..3], z[4..7]
    __shared__ int   srcs_sh[64];
    __shared__ float alpha_sh[64 * 4];
    if (t < 64) {
        int h = t & 3, slot = t >> 2;     // 16 slots per head
        float sd = s1[n * 8 + 4 + h];
        float mloc = -1e30f;
        for (int i = slot; i < deg; i += 16)
            mloc = fmaxf(mloc, leaky(s1[eidx[beg + i] * 8 + h] + sd));
        #pragma unroll
        for (int off = 4; off <= 32; off <<= 1)
            mloc = fmaxf(mloc, __shfl_xor(mloc, off));
        float zloc = 0.f;
        for (int i = slot; i < deg; i += 16)
            zloc += __expf(leaky(s1[eidx[beg + i] * 8 + h] + sd) - mloc);
        #pragma unroll
        for (int off = 4; off <= 32; off <<= 1)
            zloc += __shfl_xor(zloc, off);
        if (slot == 0) { mz[h] = mloc; mz[4 + h] = zloc; }
    }
    __syncthreads();
    float acc = 0.f;
    int h = t >> 6;
    for (int c0 = 0; c0 < deg; c0 += 64) {
        int cnt = min(64, deg - c0);
        int i = t >> 2, hh = t & 3;
        if (i < cnt) {
            int src = eidx[beg + c0 + i];
            if (hh == 0) srcs_sh[i] = src;
            float l = leaky(s1[src * 8 + hh] + s1[n * 8 + 4 + hh]);
            alpha_sh[i * 4 + hh] = __expf(l - mz[hh]) / (mz[4 + hh] + EPS);
        }
        __syncthreads();
        for (int i2 = 0; i2 < cnt; ++i2)
            acc += h1[srcs_sh[i2] * 256 + t] * alpha_sh[i2 * 4 + h];
        __syncthreads();
    }
    float v = acc + b1[t];
    out1[n * 256 + t] = v > 0.f ? v : __expf(v) - 1.f;
}

// K6: h2[N,128] = in[N,256] @ W2[256,128] — LDS-tiled, register-blocked.
__global__ __launch_bounds__(256) void k_gemm2(const float* __restrict__ in,
        const float* __restrict__ W2, const float* __restrict__ as2,
        const float* __restrict__ ad2, float* __restrict__ h2,
        float* __restrict__ s2) {
    __shared__ float As[32][68];   // A^T chunk [k][row], row stride 68
    __shared__ float Bs[32][128];  // B chunk [k][col]
    int t = threadIdx.x;
    int n0 = blockIdx.x * 64;
    int rg = t >> 4;               // 0..15 -> rows rg*4 .. rg*4+3
    int cg = t & 15;               // 0..15 -> cols cg*8 .. cg*8+7
    float acc[4][8];
    #pragma unroll
    for (int r = 0; r < 4; ++r)
        #pragma unroll
        for (int c = 0; c < 8; ++c) acc[r][c] = 0.f;

    for (int k0 = 0; k0 < 256; k0 += 32) {
        {
            int c = t & 31;
            int r0 = t >> 5;
            #pragma unroll
            for (int i = 0; i < 8; ++i) {
                int r = r0 + i * 8;
                int n = n0 + r;
                As[c][r] = (n < N_NODES) ? in[n * 256 + k0 + c] : 0.f;
            }
        }
        #pragma unroll
        for (int i = 0; i < 16; ++i) {
            int idx = i * 256 + t;
            int kk = idx >> 7, c = idx & 127;
            Bs[kk][c] = W2[(k0 + kk) * 128 + c];
        }
        __syncthreads();
        #pragma unroll 8
        for (int kk = 0; kk < 32; ++kk) {
            float4 a = *(const float4*)&As[kk][rg * 4];
            float4 b0 = *(const float4*)&Bs[kk][cg * 8];
            float4 b1v = *(const float4*)&Bs[kk][cg * 8 + 4];
            float av[4] = {a.x, a.y, a.z, a.w};
            float bv[8] = {b0.x, b0.y, b0.z, b0.w, b1v.x, b1v.y, b1v.z, b1v.w};
            #pragma unroll
            for (int r = 0; r < 4; ++r)
                #pragma unroll
                for (int c = 0; c < 8; ++c)
                    acc[r][c] += av[r] * bv[c];
        }
        __syncthreads();
    }
    float ps[4], pd[4];
    #pragma unroll
    for (int r = 0; r < 4; ++r) { ps[r] = 0.f; pd[r] = 0.f; }
    #pragma unroll
    for (int c = 0; c < 8; ++c) {
        float a_s = as2[cg * 8 + c];
        float a_d = ad2[cg * 8 + c];
        #pragma unroll
        for (int r = 0; r < 4; ++r) {
            ps[r] += acc[r][c] * a_s;
            pd[r] += acc[r][c] * a_d;
        }
    }
    #pragma unroll
    for (int r = 0; r < 4; ++r) {
        int n = n0 + rg * 4 + r;
        if (n < N_NODES) {
            float4 o0 = make_float4(acc[r][0], acc[r][1], acc[r][2], acc[r][3]);
            float4 o1 = make_float4(acc[r][4], acc[r][5], acc[r][6], acc[r][7]);
            *(float4*)(h2 + n * 128 + cg * 8) = o0;
            *(float4*)(h2 + n * 128 + cg * 8 + 4) = o1;
        }
    }
    #pragma unroll
    for (int off = 1; off <= 4; off <<= 1) {
        #pragma unroll
        for (int r = 0; r < 4; ++r) {
            ps[r] += __shfl_xor(ps[r], off);
            pd[r] += __shfl_xor(pd[r], off);
        }
    }
    if ((cg & 7) == 0) {
        int head = cg >> 3;
        #pragma unroll
        for (int r = 0; r < 4; ++r) {
            int n = n0 + rg * 4 + r;
            if (n < N_NODES) {
                s2[n * 4 + head] = ps[r];
                s2[n * 4 + 2 + head] = pd[r];
            }
        }
    }
}

// Fused layer-2: softmax stats + gather-aggregate + bias + ELU + FC + sigmoid.
__global__ __launch_bounds__(128) void k_agg2_csr(const int* __restrict__ rowptr,
        const int* __restrict__ eidx, const float* __restrict__ s2,
        const float* __restrict__ h2, const float* __restrict__ b2,
        const float* __restrict__ Wfc, const float* __restrict__ bfc,
        float* __restrict__ out) {
    int n = blockIdx.x;
    int t = threadIdx.x;
    int beg = rowptr[n];
    int deg = rowptr[n + 1] - beg;
    __shared__ float mz[4];        // m[0..1], z[2..3]
    __shared__ int   srcs_sh[64];
    __shared__ float alpha_sh[64 * 2];
    __shared__ float red[2];
    if (t < 64) {
        int h = t & 1, slot = t >> 1;    // 32 slots per head
        float sd = s2[n * 4 + 2 + h];
        float mloc = -1e30f;
        for (int i = slot; i < deg; i += 32)
            mloc = fmaxf(mloc, leaky(s2[eidx[beg + i] * 4 + h] + sd));
        #pragma unroll
        for (int off = 2; off <= 32; off <<= 1)
            mloc = fmaxf(mloc, __shfl_xor(mloc, off));
        float zloc = 0.f;
        for (int i = slot; i < deg; i += 32)
            zloc += __expf(leaky(s2[eidx[beg + i] * 4 + h] + sd) - mloc);
        #pragma unroll
        for (int off = 2; off <= 32; off <<= 1)
            zloc += __shfl_xor(zloc, off);
        if (slot == 0) { mz[h] = mloc; mz[2 + h] = zloc; }
    }
    __syncthreads();
    float acc = 0.f;
    int h = t >> 6;
    for (int c0 = 0; c0 < deg; c0 += 64) {
        int cnt = min(64, deg - c0);
        int i = t >> 1, hh = t & 1;
        if (i < cnt) {
            int src = eidx[beg + c0 + i];
            if (hh == 0) srcs_sh[i] = src;
            float l = leaky(s2[src * 4 + hh] + s2[n * 4 + 2 + hh]);
            alpha_sh[i * 2 + hh] = __expf(l - mz[hh]) / (mz[2 + hh] + EPS);
        }
        __syncthreads();
        for (int i2 = 0; i2 < cnt; ++i2)
            acc += h2[srcs_sh[i2] * 128 + t] * alpha_sh[i2 * 2 + h];
        __syncthreads();
    }
    float v = acc + b2[t];
    v = v > 0.f ? v : __expf(v) - 1.f;
    float p = v * Wfc[t];
    #pragma unroll
    for (int off = 32; off > 0; off >>= 1) p += __shfl_down(p, off);
    if ((t & 63) == 0) red[t >> 6] = p;
    __syncthreads();
    if (t == 0) out[n] = 1.f / (1.f + __expf(-(red[0] + red[1] + bfc[0])));
}

extern "C" void kernel_launch(void* const* d_in, const int* in_sizes, int n_in,
                              void* d_out, int out_size, void* d_ws, size_t ws_size,
                              hipStream_t stream) {
    const float* x   = (const float*)d_in[0];
    const int*   ei  = (const int*)d_in[1];
    const float* W1  = (const float*)d_in[2];
    const float* as1 = (const float*)d_in[3];
    const float* ad1 = (const float*)d_in[4];
    const float* b1  = (const float*)d_in[5];
    const float* W2  = (const float*)d_in[6];
    const float* as2 = (const float*)d_in[7];
    const float* ad2 = (const float*)d_in[8];
    const float* b2  = (const float*)d_in[9];
    const float* Wfc = (const float*)d_in[10];
    const float* bfc = (const float*)d_in[11];
    float* out = (float*)d_out;

    float* f = (float*)d_ws;
    float* h1     = f;                         // N*256
    float* out1   = f + 12800000;              // N*256
    float* s1     = f + 25600000;              // N*8
    float* s2     = f + 26000000;              // N*4
    int*   rowptr = (int*)(f + 26200000);      // N+1
    int*   cursor = (int*)(f + 26260000);      // N
    int*   deg    = (int*)(f + 26320000);      // N
    int*   eidx   = (int*)(f + 26380000);      // E_TOT
    int*   bsum   = (int*)(f + 26740000);      // 256
    int*   bofs   = (int*)(f + 26741000);      // 256
    float* h2     = h1;                        // alias: N*128 (h1 dead by then)

    // CSR build
    hipMemsetAsync(deg, 0, (size_t)N_NODES * 4, stream);
    k_hist<<<(E_TOT + 255) / 256, 256, 0, stream>>>(ei, deg);
    k_blocksum<<<SCAN_BLOCKS, 256, 0, stream>>>(deg, bsum);
    k_scanb<<<1, 256, 0, stream>>>(bsum, bofs);
    k_rowptr<<<SCAN_BLOCKS, 256, 0, stream>>>(deg, bofs, rowptr, cursor);
    k_scatter<<<(E_TOT + 255) / 256, 256, 0, stream>>>(ei, cursor, eidx);

    // layer 1
    k_gemm1<<<3125, 256, 0, stream>>>(x, W1, as1, ad1, h1, s1);
    k_agg1_csr<<<N_NODES, 256, 0, stream>>>(rowptr, eidx, s1, h1, b1, out1);

    // layer 2 (+ final FC + sigmoid fused)
    k_gemm2<<<(N_NODES + 63) / 64, 256, 0, stream>>>(out1, W2, as2, ad2, h2, s2);
    k_agg2_csr<<<N_NODES, 128, 0, stream>>>(rowptr, eidx, s2, h2, b2, Wfc, bfc, out);
}

// Round 5
// 371.056 us; speedup vs baseline: 2.6710x; 1.1675x over previous
//
#include <hip/hip_runtime.h>
#include <math.h>

#define N_NODES 50000
#define E_EDGES 300000
#define E_TOT   350000   // E + N self-loops
#define NEG 0.2f
#define EPS 1e-16f
#define SCAN_BLOCKS 196  // 196*256 = 50176 >= 50000

__device__ __forceinline__ float leaky(float x) { return x > 0.f ? x : NEG * x; }

// ---------------- CSR construction ----------------

__global__ __launch_bounds__(256) void k_hist(const int* __restrict__ ei,
        int* __restrict__ deg) {
    int e = blockIdx.x * 256 + threadIdx.x;
    if (e >= E_TOT) return;
    int d = (e < E_EDGES) ? ei[E_EDGES + e] : (e - E_EDGES);
    atomicAdd(&deg[d], 1);
}

__global__ __launch_bounds__(256) void k_blocksum(const int* __restrict__ deg,
        int* __restrict__ bsum) {
    int t = threadIdx.x;
    int idx = blockIdx.x * 256 + t;
    int v = (idx < N_NODES) ? deg[idx] : 0;
    #pragma unroll
    for (int off = 32; off > 0; off >>= 1) v += __shfl_down(v, off);
    __shared__ int ws[4];
    if ((t & 63) == 0) ws[t >> 6] = v;
    __syncthreads();
    if (t == 0) bsum[blockIdx.x] = ws[0] + ws[1] + ws[2] + ws[3];
}

__global__ __launch_bounds__(256) void k_scanb(const int* __restrict__ bsum,
        int* __restrict__ bofs) {
    __shared__ int sh[256];
    int t = threadIdx.x;
    sh[t] = (t < SCAN_BLOCKS) ? bsum[t] : 0;
    __syncthreads();
    for (int s = 1; s < 256; s <<= 1) {
        int v = (t >= s) ? sh[t - s] : 0;
        __syncthreads();
        sh[t] += v;
        __syncthreads();
    }
    bofs[t] = (t == 0) ? 0 : sh[t - 1];
}

__global__ __launch_bounds__(256) void k_rowptr(const int* __restrict__ deg,
        const int* __restrict__ bofs, int* __restrict__ rowptr,
        int* __restrict__ cursor) {
    __shared__ int sh[256];
    int t = threadIdx.x;
    int idx = blockIdx.x * 256 + t;
    int v = (idx < N_NODES) ? deg[idx] : 0;
    sh[t] = v;
    __syncthreads();
    for (int s = 1; s < 256; s <<= 1) {
        int u = (t >= s) ? sh[t - s] : 0;
        __syncthreads();
        sh[t] += u;
        __syncthreads();
    }
    int excl = sh[t] - v + bofs[blockIdx.x];
    if (idx < N_NODES) { rowptr[idx] = excl; cursor[idx] = excl; }
    if (idx == N_NODES) rowptr[N_NODES] = E_TOT;
}

__global__ __launch_bounds__(256) void k_scatter(const int* __restrict__ ei,
        int* __restrict__ cursor, int* __restrict__ eidx) {
    int e = blockIdx.x * 256 + threadIdx.x;
    if (e >= E_TOT) return;
    int s = (e < E_EDGES) ? ei[e] : (e - E_EDGES);
    int d = (e < E_EDGES) ? ei[E_EDGES + e] : (e - E_EDGES);
    int pos = atomicAdd(&cursor[d], 1);
    eidx[pos] = s;
}

// ---------------- layer computations ----------------

// K1: h1[N,256] = x[N,27] @ W1[27,256]; s1[n][0..3]=src half-scores, [4..7]=dst
__global__ __launch_bounds__(256) void k_gemm1(const float* __restrict__ x,
        const float* __restrict__ W1, const float* __restrict__ as1,
        const float* __restrict__ ad1, float* __restrict__ h1,
        float* __restrict__ s1) {
    __shared__ float W1s[27 * 256];
    __shared__ float xs[16 * 27];
    int t = threadIdx.x;
    for (int i = t; i < 27 * 256; i += 256) W1s[i] = W1[i];
    int base = blockIdx.x * 16;   // 3125 * 16 = 50000 exact
    for (int i = t; i < 16 * 27; i += 256) xs[i] = x[base * 27 + i];
    __syncthreads();
    float asr = as1[t], adt = ad1[t];
    int head = t >> 6;
    for (int j = 0; j < 16; ++j) {
        float acc = 0.f;
        #pragma unroll
        for (int k = 0; k < 27; ++k) acc += xs[j * 27 + k] * W1s[k * 256 + t];
        int n = base + j;
        h1[n * 256 + t] = acc;
        float ps = acc * asr, pd = acc * adt;
        #pragma unroll
        for (int off = 32; off > 0; off >>= 1) {
            ps += __shfl_down(ps, off);
            pd += __shfl_down(pd, off);
        }
        if ((t & 63) == 0) {
            s1[n * 8 + head] = ps;
            s1[n * 8 + 4 + head] = pd;
        }
    }
}

// Fused layer-1 aggregate: wave-per-node, sync-free.
// Pass 1: per-head max (shfl butterfly). Pass 2: z and Σ e*h fused; /z at end.
__global__ __launch_bounds__(256) void k_agg1_csr(const int* __restrict__ rowptr,
        const int* __restrict__ eidx, const float* __restrict__ s1,
        const float* __restrict__ h1, const float* __restrict__ b1,
        float* __restrict__ out1) {
    int wave = threadIdx.x >> 6;
    int l = threadIdx.x & 63;
    int n = blockIdx.x * 4 + wave;           // grid 12500 -> exact
    int beg = rowptr[n];
    int deg = rowptr[n + 1] - beg;
    // pass 1: max per head; lane = slot*4 + head (16 slots x 4 heads)
    int hh = l & 3;
    float sd_hh = s1[n * 8 + 4 + hh];
    float mloc = -1e30f;
    for (int i = (l >> 2); i < deg; i += 16)
        mloc = fmaxf(mloc, leaky(s1[eidx[beg + i] * 8 + hh] + sd_hh));
    #pragma unroll
    for (int off = 4; off <= 32; off <<= 1)
        mloc = fmaxf(mloc, __shfl_xor(mloc, off));
    // pass 2: lane covers channels 4l..4l+3, head = l>>4
    int h = l >> 4;
    float m = __shfl(mloc, h);               // lane h holds head-h max
    float sd = s1[n * 8 + 4 + h];
    float4 acc = make_float4(0.f, 0.f, 0.f, 0.f);
    float z = 0.f;
    for (int i = 0; i < deg; ++i) {
        int src = eidx[beg + i];
        float e = __expf(leaky(s1[src * 8 + h] + sd) - m);
        z += e;
        float4 v = *(const float4*)(h1 + src * 256 + l * 4);
        acc.x += e * v.x; acc.y += e * v.y; acc.z += e * v.z; acc.w += e * v.w;
    }
    float inv = 1.f / (z + EPS);
    float4 bb = *(const float4*)(b1 + l * 4);
    float4 o;
    o.x = acc.x * inv + bb.x; o.y = acc.y * inv + bb.y;
    o.z = acc.z * inv + bb.z; o.w = acc.w * inv + bb.w;
    o.x = o.x > 0.f ? o.x : __expf(o.x) - 1.f;
    o.y = o.y > 0.f ? o.y : __expf(o.y) - 1.f;
    o.z = o.z > 0.f ? o.z : __expf(o.z) - 1.f;
    o.w = o.w > 0.f ? o.w : __expf(o.w) - 1.f;
    *(float4*)(out1 + n * 256 + l * 4) = o;
}

// K6: h2[N,128] = in[N,256] @ W2[256,128] — LDS-tiled, register-blocked.
__global__ __launch_bounds__(256) void k_gemm2(const float* __restrict__ in,
        const float* __restrict__ W2, const float* __restrict__ as2,
        const float* __restrict__ ad2, float* __restrict__ h2,
        float* __restrict__ s2) {
    __shared__ float As[32][68];   // A^T chunk [k][row], row stride 68
    __shared__ float Bs[32][128];  // B chunk [k][col]
    int t = threadIdx.x;
    int n0 = blockIdx.x * 64;
    int rg = t >> 4;               // 0..15 -> rows rg*4 .. rg*4+3
    int cg = t & 15;               // 0..15 -> cols cg*8 .. cg*8+7
    float acc[4][8];
    #pragma unroll
    for (int r = 0; r < 4; ++r)
        #pragma unroll
        for (int c = 0; c < 8; ++c) acc[r][c] = 0.f;

    for (int k0 = 0; k0 < 256; k0 += 32) {
        {
            int c = t & 31;
            int r0 = t >> 5;
            #pragma unroll
            for (int i = 0; i < 8; ++i) {
                int r = r0 + i * 8;
                int n = n0 + r;
                As[c][r] = (n < N_NODES) ? in[n * 256 + k0 + c] : 0.f;
            }
        }
        #pragma unroll
        for (int i = 0; i < 16; ++i) {
            int idx = i * 256 + t;
            int kk = idx >> 7, c = idx & 127;
            Bs[kk][c] = W2[(k0 + kk) * 128 + c];
        }
        __syncthreads();
        #pragma unroll 8
        for (int kk = 0; kk < 32; ++kk) {
            float4 a = *(const float4*)&As[kk][rg * 4];
            float4 b0 = *(const float4*)&Bs[kk][cg * 8];
            float4 b1v = *(const float4*)&Bs[kk][cg * 8 + 4];
            float av[4] = {a.x, a.y, a.z, a.w};
            float bv[8] = {b0.x, b0.y, b0.z, b0.w, b1v.x, b1v.y, b1v.z, b1v.w};
            #pragma unroll
            for (int r = 0; r < 4; ++r)
                #pragma unroll
                for (int c = 0; c < 8; ++c)
                    acc[r][c] += av[r] * bv[c];
        }
        __syncthreads();
    }
    float ps[4], pd[4];
    #pragma unroll
    for (int r = 0; r < 4; ++r) { ps[r] = 0.f; pd[r] = 0.f; }
    #pragma unroll
    for (int c = 0; c < 8; ++c) {
        float a_s = as2[cg * 8 + c];
        float a_d = ad2[cg * 8 + c];
        #pragma unroll
        for (int r = 0; r < 4; ++r) {
            ps[r] += acc[r][c] * a_s;
            pd[r] += acc[r][c] * a_d;
        }
    }
    #pragma unroll
    for (int r = 0; r < 4; ++r) {
        int n = n0 + rg * 4 + r;
        if (n < N_NODES) {
            float4 o0 = make_float4(acc[r][0], acc[r][1], acc[r][2], acc[r][3]);
            float4 o1 = make_float4(acc[r][4], acc[r][5], acc[r][6], acc[r][7]);
            *(float4*)(h2 + n * 128 + cg * 8) = o0;
            *(float4*)(h2 + n * 128 + cg * 8 + 4) = o1;
        }
    }
    #pragma unroll
    for (int off = 1; off <= 4; off <<= 1) {
        #pragma unroll
        for (int r = 0; r < 4; ++r) {
            ps[r] += __shfl_xor(ps[r], off);
            pd[r] += __shfl_xor(pd[r], off);
        }
    }
    if ((cg & 7) == 0) {
        int head = cg >> 3;
        #pragma unroll
        for (int r = 0; r < 4; ++r) {
            int n = n0 + rg * 4 + r;
            if (n < N_NODES) {
                s2[n * 4 + head] = ps[r];
                s2[n * 4 + 2 + head] = pd[r];
            }
        }
    }
}

// Fused layer-2 aggregate: wave-per-node, sync-free, + bias/ELU/FC/sigmoid.
__global__ __launch_bounds__(256) void k_agg2_csr(const int* __restrict__ rowptr,
        const int* __restrict__ eidx, const float* __restrict__ s2,
        const float* __restrict__ h2, const float* __restrict__ b2,
        const float* __restrict__ Wfc, const float* __restrict__ bfc,
        float* __restrict__ out) {
    int wave = threadIdx.x >> 6;
    int l = threadIdx.x & 63;
    int n = blockIdx.x * 4 + wave;           // grid 12500 -> exact
    int beg = rowptr[n];
    int deg = rowptr[n + 1] - beg;
    // pass 1: max per head; lane = slot*2 + head (32 slots x 2 heads)
    int hh = l & 1;
    float sd_hh = s2[n * 4 + 2 + hh];
    float mloc = -1e30f;
    for (int i = (l >> 1); i < deg; i += 32)
        mloc = fmaxf(mloc, leaky(s2[eidx[beg + i] * 4 + hh] + sd_hh));
    #pragma unroll
    for (int off = 2; off <= 32; off <<= 1)
        mloc = fmaxf(mloc, __shfl_xor(mloc, off));
    // pass 2: lane covers channels 2l..2l+1, head = l>>5
    int h = l >> 5;
    float m = __shfl(mloc, h);               // lane h holds head-h max
    float sd = s2[n * 4 + 2 + h];
    float2 acc = make_float2(0.f, 0.f);
    float z = 0.f;
    for (int i = 0; i < deg; ++i) {
        int src = eidx[beg + i];
        float e = __expf(leaky(s2[src * 4 + h] + sd) - m);
        z += e;
        float2 v = *(const float2*)(h2 + src * 128 + l * 2);
        acc.x += e * v.x; acc.y += e * v.y;
    }
    float inv = 1.f / (z + EPS);
    float v0 = acc.x * inv + b2[l * 2];
    float v1 = acc.y * inv + b2[l * 2 + 1];
    v0 = v0 > 0.f ? v0 : __expf(v0) - 1.f;
    v1 = v1 > 0.f ? v1 : __expf(v1) - 1.f;
    float p = v0 * Wfc[l * 2] + v1 * Wfc[l * 2 + 1];
    #pragma unroll
    for (int off = 1; off <= 32; off <<= 1) p += __shfl_xor(p, off);
    if (l == 0) out[n] = 1.f / (1.f + __expf(-(p + bfc[0])));
}

extern "C" void kernel_launch(void* const* d_in, const int* in_sizes, int n_in,
                              void* d_out, int out_size, void* d_ws, size_t ws_size,
                              hipStream_t stream) {
    const float* x   = (const float*)d_in[0];
    const int*   ei  = (const int*)d_in[1];
    const float* W1  = (const float*)d_in[2];
    const float* as1 = (const float*)d_in[3];
    const float* ad1 = (const float*)d_in[4];
    const float* b1  = (const float*)d_in[5];
    const float* W2  = (const float*)d_in[6];
    const float* as2 = (const float*)d_in[7];
    const float* ad2 = (const float*)d_in[8];
    const float* b2  = (const float*)d_in[9];
    const float* Wfc = (const float*)d_in[10];
    const float* bfc = (const float*)d_in[11];
    float* out = (float*)d_out;

    float* f = (float*)d_ws;
    float* h1     = f;                         // N*256
    float* out1   = f + 12800000;              // N*256
    float* s1     = f + 25600000;              // N*8
    float* s2     = f + 26000000;              // N*4
    int*   rowptr = (int*)(f + 26200000);      // N+1
    int*   cursor = (int*)(f + 26260000);      // N
    int*   deg    = (int*)(f + 26320000);      // N
    int*   eidx   = (int*)(f + 26380000);      // E_TOT
    int*   bsum   = (int*)(f + 26740000);      // 256
    int*   bofs   = (int*)(f + 26741000);      // 256
    float* h2     = h1;                        // alias: N*128 (h1 dead by then)

    // CSR build
    hipMemsetAsync(deg, 0, (size_t)N_NODES * 4, stream);
    k_hist<<<(E_TOT + 255) / 256, 256, 0, stream>>>(ei, deg);
    k_blocksum<<<SCAN_BLOCKS, 256, 0, stream>>>(deg, bsum);
    k_scanb<<<1, 256, 0, stream>>>(bsum, bofs);
    k_rowptr<<<SCAN_BLOCKS, 256, 0, stream>>>(deg, bofs, rowptr, cursor);
    k_scatter<<<(E_TOT + 255) / 256, 256, 0, stream>>>(ei, cursor, eidx);

    // layer 1
    k_gemm1<<<3125, 256, 0, stream>>>(x, W1, as1, ad1, h1, s1);
    k_agg1_csr<<<12500, 256, 0, stream>>>(rowptr, eidx, s1, h1, b1, out1);

    // layer 2 (+ final FC + sigmoid fused)
    k_gemm2<<<(N_NODES + 63) / 64, 256, 0, stream>>>(out1, W2, as2, ad2, h2, s2);
    k_agg2_csr<<<12500, 256, 0, stream>>>(rowptr, eidx, s2, h2, b2, Wfc, bfc, out);
}

// Round 6
// 360.430 us; speedup vs baseline: 2.7497x; 1.0295x over previous
//
#include <hip/hip_runtime.h>
#include <math.h>

#define N_NODES 50000
#define E_EDGES 300000
#define E_TOT   350000   // E + N self-loops
#define NEG 0.2f
#define EPS 1e-16f
#define SCAN_BLOCKS 196  // 196*256 = 50176 >= 50000
#define BS_STRIDE 140    // swizzled B row: 35 float4s (f' = f + (f>>3), max 34)

__device__ __forceinline__ float leaky(float x) { return x > 0.f ? x : NEG * x; }

// ---------------- CSR construction ----------------

__global__ __launch_bounds__(256) void k_hist(const int* __restrict__ ei,
        int* __restrict__ deg) {
    int e = blockIdx.x * 256 + threadIdx.x;
    if (e >= E_TOT) return;
    int d = (e < E_EDGES) ? ei[E_EDGES + e] : (e - E_EDGES);
    atomicAdd(&deg[d], 1);
}

__global__ __launch_bounds__(256) void k_blocksum(const int* __restrict__ deg,
        int* __restrict__ bsum) {
    int t = threadIdx.x;
    int idx = blockIdx.x * 256 + t;
    int v = (idx < N_NODES) ? deg[idx] : 0;
    #pragma unroll
    for (int off = 32; off > 0; off >>= 1) v += __shfl_down(v, off);
    __shared__ int ws[4];
    if ((t & 63) == 0) ws[t >> 6] = v;
    __syncthreads();
    if (t == 0) bsum[blockIdx.x] = ws[0] + ws[1] + ws[2] + ws[3];
}

__global__ __launch_bounds__(256) void k_scanb(const int* __restrict__ bsum,
        int* __restrict__ bofs) {
    __shared__ int sh[256];
    int t = threadIdx.x;
    sh[t] = (t < SCAN_BLOCKS) ? bsum[t] : 0;
    __syncthreads();
    for (int s = 1; s < 256; s <<= 1) {
        int v = (t >= s) ? sh[t - s] : 0;
        __syncthreads();
        sh[t] += v;
        __syncthreads();
    }
    bofs[t] = (t == 0) ? 0 : sh[t - 1];
}

__global__ __launch_bounds__(256) void k_rowptr(const int* __restrict__ deg,
        const int* __restrict__ bofs, int* __restrict__ rowptr,
        int* __restrict__ cursor) {
    __shared__ int sh[256];
    int t = threadIdx.x;
    int idx = blockIdx.x * 256 + t;
    int v = (idx < N_NODES) ? deg[idx] : 0;
    sh[t] = v;
    __syncthreads();
    for (int s = 1; s < 256; s <<= 1) {
        int u = (t >= s) ? sh[t - s] : 0;
        __syncthreads();
        sh[t] += u;
        __syncthreads();
    }
    int excl = sh[t] - v + bofs[blockIdx.x];
    if (idx < N_NODES) { rowptr[idx] = excl; cursor[idx] = excl; }
    if (idx == N_NODES) rowptr[N_NODES] = E_TOT;
}

__global__ __launch_bounds__(256) void k_scatter(const int* __restrict__ ei,
        int* __restrict__ cursor, int* __restrict__ eidx) {
    int e = blockIdx.x * 256 + threadIdx.x;
    if (e >= E_TOT) return;
    int s = (e < E_EDGES) ? ei[e] : (e - E_EDGES);
    int d = (e < E_EDGES) ? ei[E_EDGES + e] : (e - E_EDGES);
    int pos = atomicAdd(&cursor[d], 1);
    eidx[pos] = s;
}

// ---------------- layer computations ----------------

// K1: h1[N,256] = x[N,27] @ W1[27,256]; s1[n][0..3]=src half-scores, [4..7]=dst
__global__ __launch_bounds__(256) void k_gemm1(const float* __restrict__ x,
        const float* __restrict__ W1, const float* __restrict__ as1,
        const float* __restrict__ ad1, float* __restrict__ h1,
        float* __restrict__ s1) {
    __shared__ float W1s[27 * 256];
    __shared__ float xs[16 * 27];
    int t = threadIdx.x;
    for (int i = t; i < 27 * 256; i += 256) W1s[i] = W1[i];
    int base = blockIdx.x * 16;   // 3125 * 16 = 50000 exact
    for (int i = t; i < 16 * 27; i += 256) xs[i] = x[base * 27 + i];
    __syncthreads();
    float asr = as1[t], adt = ad1[t];
    int head = t >> 6;
    for (int j = 0; j < 16; ++j) {
        float acc = 0.f;
        #pragma unroll
        for (int k = 0; k < 27; ++k) acc += xs[j * 27 + k] * W1s[k * 256 + t];
        int n = base + j;
        h1[n * 256 + t] = acc;
        float ps = acc * asr, pd = acc * adt;
        #pragma unroll
        for (int off = 32; off > 0; off >>= 1) {
            ps += __shfl_down(ps, off);
            pd += __shfl_down(pd, off);
        }
        if ((t & 63) == 0) {
            s1[n * 8 + head] = ps;
            s1[n * 8 + 4 + head] = pd;
        }
    }
}

// Fused layer-1 aggregate: wave-per-node, sync-free.
__global__ __launch_bounds__(256) void k_agg1_csr(const int* __restrict__ rowptr,
        const int* __restrict__ eidx, const float* __restrict__ s1,
        const float* __restrict__ h1, const float* __restrict__ b1,
        float* __restrict__ out1) {
    int wave = threadIdx.x >> 6;
    int l = threadIdx.x & 63;
    int n = blockIdx.x * 4 + wave;           // grid 12500 -> exact
    int beg = rowptr[n];
    int deg = rowptr[n + 1] - beg;
    int hh = l & 3;
    float sd_hh = s1[n * 8 + 4 + hh];
    float mloc = -1e30f;
    for (int i = (l >> 2); i < deg; i += 16)
        mloc = fmaxf(mloc, leaky(s1[eidx[beg + i] * 8 + hh] + sd_hh));
    #pragma unroll
    for (int off = 4; off <= 32; off <<= 1)
        mloc = fmaxf(mloc, __shfl_xor(mloc, off));
    int h = l >> 4;
    float m = __shfl(mloc, h);
    float sd = s1[n * 8 + 4 + h];
    float4 acc = make_float4(0.f, 0.f, 0.f, 0.f);
    float z = 0.f;
    for (int i = 0; i < deg; ++i) {
        int src = eidx[beg + i];
        float e = __expf(leaky(s1[src * 8 + h] + sd) - m);
        z += e;
        float4 v = *(const float4*)(h1 + src * 256 + l * 4);
        acc.x += e * v.x; acc.y += e * v.y; acc.z += e * v.z; acc.w += e * v.w;
    }
    float inv = 1.f / (z + EPS);
    float4 bb = *(const float4*)(b1 + l * 4);
    float4 o;
    o.x = acc.x * inv + bb.x; o.y = acc.y * inv + bb.y;
    o.z = acc.z * inv + bb.z; o.w = acc.w * inv + bb.w;
    o.x = o.x > 0.f ? o.x : __expf(o.x) - 1.f;
    o.y = o.y > 0.f ? o.y : __expf(o.y) - 1.f;
    o.z = o.z > 0.f ? o.z : __expf(o.z) - 1.f;
    o.w = o.w > 0.f ? o.w : __expf(o.w) - 1.f;
    *(float4*)(out1 + n * 256 + l * 4) = o;
}

// K6: h2[N,128] = in[N,256] @ W2[256,128] — LDS-tiled, conflict-free layout.
// As [k][row] pad+4: writes lane==row (2-way, free), reads broadcast.
// Bs swizzled f' = f + (f>>3) at float4 granularity: reads/writes 2-way, free.
__global__ __launch_bounds__(256) void k_gemm2(const float* __restrict__ in,
        const float* __restrict__ W2, const float* __restrict__ as2,
        const float* __restrict__ ad2, float* __restrict__ h2,
        float* __restrict__ s2) {
    __shared__ float As[32][68];
    __shared__ float Bs[32 * BS_STRIDE];
    int t = threadIdx.x;
    int n0 = blockIdx.x * 64;
    int rg = t >> 4;               // 0..15 -> rows rg*4 .. rg*4+3
    int cg = t & 15;               // 0..15 -> cols cg*8 .. cg*8+7
    int f0 = 2 * cg, f1 = 2 * cg + 1;
    int bo0 = (f0 + (f0 >> 3)) * 4;
    int bo1 = (f1 + (f1 >> 3)) * 4;
    int sr = t & 63;               // staging row (lane id -> conflict-free writes)
    int sc = (t >> 6) * 8;         // staging k-offset per wave
    float acc[4][8];
    #pragma unroll
    for (int r = 0; r < 4; ++r)
        #pragma unroll
        for (int c = 0; c < 8; ++c) acc[r][c] = 0.f;

    for (int k0 = 0; k0 < 256; k0 += 32) {
        // stage A: thread owns row sr, 8 consecutive k
        {
            int n = n0 + sr;
            float4 va = make_float4(0.f, 0.f, 0.f, 0.f), vb = va;
            if (n < N_NODES) {
                va = *(const float4*)(in + n * 256 + k0 + sc);
                vb = *(const float4*)(in + n * 256 + k0 + sc + 4);
            }
            As[sc + 0][sr] = va.x; As[sc + 1][sr] = va.y;
            As[sc + 2][sr] = va.z; As[sc + 3][sr] = va.w;
            As[sc + 4][sr] = vb.x; As[sc + 5][sr] = vb.y;
            As[sc + 6][sr] = vb.z; As[sc + 7][sr] = vb.w;
        }
        // stage B: swizzled scatter, coalesced global read
        #pragma unroll
        for (int i = 0; i < 16; ++i) {
            int idx = i * 256 + t;
            int kk = idx >> 7, c = idx & 127;
            int fq = c >> 2;
            Bs[kk * BS_STRIDE + (fq + (fq >> 3)) * 4 + (c & 3)] =
                W2[(k0 + kk) * 128 + c];
        }
        __syncthreads();
        #pragma unroll 8
        for (int kk = 0; kk < 32; ++kk) {
            float4 a = *(const float4*)&As[kk][rg * 4];
            float4 b0 = *(const float4*)&Bs[kk * BS_STRIDE + bo0];
            float4 b1v = *(const float4*)&Bs[kk * BS_STRIDE + bo1];
            float av[4] = {a.x, a.y, a.z, a.w};
            float bv[8] = {b0.x, b0.y, b0.z, b0.w, b1v.x, b1v.y, b1v.z, b1v.w};
            #pragma unroll
            for (int r = 0; r < 4; ++r)
                #pragma unroll
                for (int c = 0; c < 8; ++c)
                    acc[r][c] += av[r] * bv[c];
        }
        __syncthreads();
    }
    float ps[4], pd[4];
    #pragma unroll
    for (int r = 0; r < 4; ++r) { ps[r] = 0.f; pd[r] = 0.f; }
    #pragma unroll
    for (int c = 0; c < 8; ++c) {
        float a_s = as2[cg * 8 + c];
        float a_d = ad2[cg * 8 + c];
        #pragma unroll
        for (int r = 0; r < 4; ++r) {
            ps[r] += acc[r][c] * a_s;
            pd[r] += acc[r][c] * a_d;
        }
    }
    #pragma unroll
    for (int r = 0; r < 4; ++r) {
        int n = n0 + rg * 4 + r;
        if (n < N_NODES) {
            float4 o0 = make_float4(acc[r][0], acc[r][1], acc[r][2], acc[r][3]);
            float4 o1 = make_float4(acc[r][4], acc[r][5], acc[r][6], acc[r][7]);
            *(float4*)(h2 + n * 128 + cg * 8) = o0;
            *(float4*)(h2 + n * 128 + cg * 8 + 4) = o1;
        }
    }
    #pragma unroll
    for (int off = 1; off <= 4; off <<= 1) {
        #pragma unroll
        for (int r = 0; r < 4; ++r) {
            ps[r] += __shfl_xor(ps[r], off);
            pd[r] += __shfl_xor(pd[r], off);
        }
    }
    if ((cg & 7) == 0) {
        int head = cg >> 3;
        #pragma unroll
        for (int r = 0; r < 4; ++r) {
            int n = n0 + rg * 4 + r;
            if (n < N_NODES) {
                s2[n * 4 + head] = ps[r];
                s2[n * 4 + 2 + head] = pd[r];
            }
        }
    }
}

// Fused layer-2 aggregate: wave-per-node, sync-free, + bias/ELU/FC/sigmoid.
__global__ __launch_bounds__(256) void k_agg2_csr(const int* __restrict__ rowptr,
        const int* __restrict__ eidx, const float* __restrict__ s2,
        const float* __restrict__ h2, const float* __restrict__ b2,
        const float* __restrict__ Wfc, const float* __restrict__ bfc,
        float* __restrict__ out) {
    int wave = threadIdx.x >> 6;
    int l = threadIdx.x & 63;
    int n = blockIdx.x * 4 + wave;           // grid 12500 -> exact
    int beg = rowptr[n];
    int deg = rowptr[n + 1] - beg;
    int hh = l & 1;
    float sd_hh = s2[n * 4 + 2 + hh];
    float mloc = -1e30f;
    for (int i = (l >> 1); i < deg; i += 32)
        mloc = fmaxf(mloc, leaky(s2[eidx[beg + i] * 4 + hh] + sd_hh));
    #pragma unroll
    for (int off = 2; off <= 32; off <<= 1)
        mloc = fmaxf(mloc, __shfl_xor(mloc, off));
    int h = l >> 5;
    float m = __shfl(mloc, h);
    float sd = s2[n * 4 + 2 + h];
    float2 acc = make_float2(0.f, 0.f);
    float z = 0.f;
    for (int i = 0; i < deg; ++i) {
        int src = eidx[beg + i];
        float e = __expf(leaky(s2[src * 4 + h] + sd) - m);
        z += e;
        float2 v = *(const float2*)(h2 + src * 128 + l * 2);
        acc.x += e * v.x; acc.y += e * v.y;
    }
    float inv = 1.f / (z + EPS);
    float v0 = acc.x * inv + b2[l * 2];
    float v1 = acc.y * inv + b2[l * 2 + 1];
    v0 = v0 > 0.f ? v0 : __expf(v0) - 1.f;
    v1 = v1 > 0.f ? v1 : __expf(v1) - 1.f;
    float p = v0 * Wfc[l * 2] + v1 * Wfc[l * 2 + 1];
    #pragma unroll
    for (int off = 1; off <= 32; off <<= 1) p += __shfl_xor(p, off);
    if (l == 0) out[n] = 1.f / (1.f + __expf(-(p + bfc[0])));
}

extern "C" void kernel_launch(void* const* d_in, const int* in_sizes, int n_in,
                              void* d_out, int out_size, void* d_ws, size_t ws_size,
                              hipStream_t stream) {
    const float* x   = (const float*)d_in[0];
    const int*   ei  = (const int*)d_in[1];
    const float* W1  = (const float*)d_in[2];
    const float* as1 = (const float*)d_in[3];
    const float* ad1 = (const float*)d_in[4];
    const float* b1  = (const float*)d_in[5];
    const float* W2  = (const float*)d_in[6];
    const float* as2 = (const float*)d_in[7];
    const float* ad2 = (const float*)d_in[8];
    const float* b2  = (const float*)d_in[9];
    const float* Wfc = (const float*)d_in[10];
    const float* bfc = (const float*)d_in[11];
    float* out = (float*)d_out;

    float* f = (float*)d_ws;
    float* h1     = f;                         // N*256
    float* out1   = f + 12800000;              // N*256
    float* s1     = f + 25600000;              // N*8
    float* s2     = f + 26000000;              // N*4
    int*   rowptr = (int*)(f + 26200000);      // N+1
    int*   cursor = (int*)(f + 26260000);      // N
    int*   deg    = (int*)(f + 26320000);      // N
    int*   eidx   = (int*)(f + 26380000);      // E_TOT
    int*   bsum   = (int*)(f + 26740000);      // 256
    int*   bofs   = (int*)(f + 26741000);      // 256
    float* h2     = h1;                        // alias: N*128 (h1 dead by then)

    // CSR build
    hipMemsetAsync(deg, 0, (size_t)N_NODES * 4, stream);
    k_hist<<<(E_TOT + 255) / 256, 256, 0, stream>>>(ei, deg);
    k_blocksum<<<SCAN_BLOCKS, 256, 0, stream>>>(deg, bsum);
    k_scanb<<<1, 256, 0, stream>>>(bsum, bofs);
    k_rowptr<<<SCAN_BLOCKS, 256, 0, stream>>>(deg, bofs, rowptr, cursor);
    k_scatter<<<(E_TOT + 255) / 256, 256, 0, stream>>>(ei, cursor, eidx);

    // layer 1
    k_gemm1<<<3125, 256, 0, stream>>>(x, W1, as1, ad1, h1, s1);
    k_agg1_csr<<<12500, 256, 0, stream>>>(rowptr, eidx, s1, h1, b1, out1);

    // layer 2 (+ final FC + sigmoid fused)
    k_gemm2<<<(N_NODES + 63) / 64, 256, 0, stream>>>(out1, W2, as2, ad2, h2, s2);
    k_agg2_csr<<<12500, 256, 0, stream>>>(rowptr, eidx, s2, h2, b2, Wfc, bfc, out);
}

// Round 7
// 299.948 us; speedup vs baseline: 3.3042x; 1.2016x over previous
//
#include <hip/hip_runtime.h>
#include <math.h>

#define N_NODES 50000
#define E_EDGES 300000
#define E_TOT   350000   // E + N self-loops
#define NEG 0.2f
#define EPS 1e-16f
#define SCAN_BLOCKS 196  // 196*256 = 50176 >= 50000

typedef __attribute__((ext_vector_type(8))) short bf16x8;
typedef __attribute__((ext_vector_type(4))) float f32x4;

__device__ __forceinline__ float leaky(float x) { return x > 0.f ? x : NEG * x; }
// fp32 -> bf16 (RNE, finite inputs)
__device__ __forceinline__ short f2bf(float v) {
    unsigned u = __float_as_uint(v);
    u += 0x7fffu + ((u >> 16) & 1u);
    return (short)(u >> 16);
}
__device__ __forceinline__ float bflo(unsigned u) { return __uint_as_float(u << 16); }
__device__ __forceinline__ float bfhi(unsigned u) { return __uint_as_float(u & 0xffff0000u); }
__device__ __forceinline__ unsigned bfpack(short a, short b) {
    return (unsigned)(unsigned short)a | ((unsigned)(unsigned short)b << 16);
}

// ---------------- CSR construction ----------------

__global__ __launch_bounds__(256) void k_hist(const int* __restrict__ ei,
        int* __restrict__ deg) {
    int e = blockIdx.x * 256 + threadIdx.x;
    if (e >= E_TOT) return;
    int d = (e < E_EDGES) ? ei[E_EDGES + e] : (e - E_EDGES);
    atomicAdd(&deg[d], 1);
}

__global__ __launch_bounds__(256) void k_blocksum(const int* __restrict__ deg,
        int* __restrict__ bsum) {
    int t = threadIdx.x;
    int idx = blockIdx.x * 256 + t;
    int v = (idx < N_NODES) ? deg[idx] : 0;
    #pragma unroll
    for (int off = 32; off > 0; off >>= 1) v += __shfl_down(v, off);
    __shared__ int ws[4];
    if ((t & 63) == 0) ws[t >> 6] = v;
    __syncthreads();
    if (t == 0) bsum[blockIdx.x] = ws[0] + ws[1] + ws[2] + ws[3];
}

__global__ __launch_bounds__(256) void k_scanb(const int* __restrict__ bsum,
        int* __restrict__ bofs) {
    __shared__ int sh[256];
    int t = threadIdx.x;
    sh[t] = (t < SCAN_BLOCKS) ? bsum[t] : 0;
    __syncthreads();
    for (int s = 1; s < 256; s <<= 1) {
        int v = (t >= s) ? sh[t - s] : 0;
        __syncthreads();
        sh[t] += v;
        __syncthreads();
    }
    bofs[t] = (t == 0) ? 0 : sh[t - 1];
}

__global__ __launch_bounds__(256) void k_rowptr(const int* __restrict__ deg,
        const int* __restrict__ bofs, int* __restrict__ rowptr,
        int* __restrict__ cursor) {
    __shared__ int sh[256];
    int t = threadIdx.x;
    int idx = blockIdx.x * 256 + t;
    int v = (idx < N_NODES) ? deg[idx] : 0;
    sh[t] = v;
    __syncthreads();
    for (int s = 1; s < 256; s <<= 1) {
        int u = (t >= s) ? sh[t - s] : 0;
        __syncthreads();
        sh[t] += u;
        __syncthreads();
    }
    int excl = sh[t] - v + bofs[blockIdx.x];
    if (idx < N_NODES) { rowptr[idx] = excl; cursor[idx] = excl; }
    if (idx == N_NODES) rowptr[N_NODES] = E_TOT;
}

__global__ __launch_bounds__(256) void k_scatter(const int* __restrict__ ei,
        int* __restrict__ cursor, int* __restrict__ eidx) {
    int e = blockIdx.x * 256 + threadIdx.x;
    if (e >= E_TOT) return;
    int s = (e < E_EDGES) ? ei[e] : (e - E_EDGES);
    int d = (e < E_EDGES) ? ei[E_EDGES + e] : (e - E_EDGES);
    int pos = atomicAdd(&cursor[d], 1);
    eidx[pos] = s;
}

// ---------------- bf16 prep ----------------

// xb[N,32] bf16 (zero-padded from x[N,27])
__global__ __launch_bounds__(256) void k_prep_x(const float* __restrict__ x,
        short* __restrict__ xb) {
    int n = blockIdx.x * 8 + (threadIdx.x >> 5);   // 6250*8 = 50000 exact
    int c = threadIdx.x & 31;
    float v = (c < 27) ? x[n * 27 + c] : 0.f;
    xb[n * 32 + c] = f2bf(v);
}

// W1bT[256,32] = W1^T zero-padded; W2bT[128,256] = W2^T  (both bf16)
__global__ __launch_bounds__(256) void k_prep_w(const float* __restrict__ W1,
        const float* __restrict__ W2, short* __restrict__ W1bT,
        short* __restrict__ W2bT) {
    int t = blockIdx.x * 256 + threadIdx.x;        // grid 128 -> 32768 threads
    if (t < 256 * 32) {
        int n = t >> 5, k = t & 31;
        W1bT[t] = f2bf(k < 27 ? W1[k * 256 + n] : 0.f);
    }
    {
        int n = t >> 8, k = t & 255;
        W2bT[t] = f2bf(W2[k * 128 + n]);
    }
}

// ---------------- MFMA GEMMs (no LDS, no barriers) ----------------

// h1[N,256] = xb @ W1; one wave = 16 rows; 16 col-tiles; K=32 (one MFMA each).
// Emits h1b (bf16) and s1[n][0..3]=src, [4..7]=dst half-scores (fp32).
__global__ __launch_bounds__(256) void k_gemm1(const short* __restrict__ xb,
        const short* __restrict__ W1bT, const float* __restrict__ as1,
        const float* __restrict__ ad1, short* __restrict__ h1b,
        float* __restrict__ s1) {
    int wave = threadIdx.x >> 6, l = threadIdx.x & 63;
    int m0 = (blockIdx.x * 4 + wave) * 16;
    if (m0 >= N_NODES) return;
    int lane16 = l & 15, quad = l >> 4;
    bf16x8 a = *(const bf16x8*)(xb + (m0 + lane16) * 32 + quad * 8);
    f32x4 acc[16];
    f32x4 z4 = {0.f, 0.f, 0.f, 0.f};
    #pragma unroll
    for (int nt = 0; nt < 16; ++nt) {
        bf16x8 b = *(const bf16x8*)(W1bT + (nt * 16 + lane16) * 32 + quad * 8);
        acc[nt] = __builtin_amdgcn_mfma_f32_16x16x32_bf16(a, b, z4, 0, 0, 0);
    }
    // h1b writes: D[row=quad*4+r][col=nt*16+lane16]
    #pragma unroll
    for (int nt = 0; nt < 16; ++nt)
        #pragma unroll
        for (int r = 0; r < 4; ++r)
            h1b[(m0 + quad * 4 + r) * 256 + nt * 16 + lane16] = f2bf(acc[nt][r]);
    // s1 half-scores: head = col>>6 = nt>>2
    float ps[4][4], pd[4][4];
    #pragma unroll
    for (int h = 0; h < 4; ++h)
        #pragma unroll
        for (int r = 0; r < 4; ++r) { ps[h][r] = 0.f; pd[h][r] = 0.f; }
    #pragma unroll
    for (int nt = 0; nt < 16; ++nt) {
        int col = nt * 16 + lane16;
        float a_s = as1[col], a_d = ad1[col];
        int h = nt >> 2;
        #pragma unroll
        for (int r = 0; r < 4; ++r) {
            ps[h][r] += acc[nt][r] * a_s;
            pd[h][r] += acc[nt][r] * a_d;
        }
    }
    #pragma unroll
    for (int off = 1; off <= 8; off <<= 1)
        #pragma unroll
        for (int h = 0; h < 4; ++h)
            #pragma unroll
            for (int r = 0; r < 4; ++r) {
                ps[h][r] += __shfl_xor(ps[h][r], off);
                pd[h][r] += __shfl_xor(pd[h][r], off);
            }
    int wh = lane16 >> 2, wr = lane16 & 3;       // all 16 lane16 values used
    int wn = m0 + quad * 4 + wr;
    s1[wn * 8 + wh] = ps[wh][wr];
    s1[wn * 8 + 4 + wh] = pd[wh][wr];
}

// h2[N,128] = out1b @ W2; wave = 16 rows; 8 col-tiles; K-loop 8x32.
__global__ __launch_bounds__(256) void k_gemm2(const short* __restrict__ out1b,
        const short* __restrict__ W2bT, const float* __restrict__ as2,
        const float* __restrict__ ad2, short* __restrict__ h2b,
        float* __restrict__ s2) {
    int wave = threadIdx.x >> 6, l = threadIdx.x & 63;
    int m0 = (blockIdx.x * 4 + wave) * 16;
    if (m0 >= N_NODES) return;
    int lane16 = l & 15, quad = l >> 4;
    f32x4 acc[8];
    f32x4 z4 = {0.f, 0.f, 0.f, 0.f};
    #pragma unroll
    for (int nt = 0; nt < 8; ++nt) acc[nt] = z4;
    for (int k0 = 0; k0 < 256; k0 += 32) {
        bf16x8 a = *(const bf16x8*)(out1b + (m0 + lane16) * 256 + k0 + quad * 8);
        #pragma unroll
        for (int nt = 0; nt < 8; ++nt) {
            bf16x8 b = *(const bf16x8*)(W2bT + (nt * 16 + lane16) * 256 + k0 + quad * 8);
            acc[nt] = __builtin_amdgcn_mfma_f32_16x16x32_bf16(a, b, acc[nt], 0, 0, 0);
        }
    }
    #pragma unroll
    for (int nt = 0; nt < 8; ++nt)
        #pragma unroll
        for (int r = 0; r < 4; ++r)
            h2b[(m0 + quad * 4 + r) * 128 + nt * 16 + lane16] = f2bf(acc[nt][r]);
    // s2: head = col>>6 = nt>>2 (0..1)
    float ps[2][4], pd[2][4];
    #pragma unroll
    for (int h = 0; h < 2; ++h)
        #pragma unroll
        for (int r = 0; r < 4; ++r) { ps[h][r] = 0.f; pd[h][r] = 0.f; }
    #pragma unroll
    for (int nt = 0; nt < 8; ++nt) {
        int col = nt * 16 + lane16;
        float a_s = as2[col], a_d = ad2[col];
        int h = nt >> 2;
        #pragma unroll
        for (int r = 0; r < 4; ++r) {
            ps[h][r] += acc[nt][r] * a_s;
            pd[h][r] += acc[nt][r] * a_d;
        }
    }
    #pragma unroll
    for (int off = 1; off <= 8; off <<= 1)
        #pragma unroll
        for (int h = 0; h < 2; ++h)
            #pragma unroll
            for (int r = 0; r < 4; ++r) {
                ps[h][r] += __shfl_xor(ps[h][r], off);
                pd[h][r] += __shfl_xor(pd[h][r], off);
            }
    if (lane16 < 8) {
        int wh = lane16 >> 2, wr = lane16 & 3;
        int wn = m0 + quad * 4 + wr;
        s2[wn * 4 + wh] = ps[wh][wr];
        s2[wn * 4 + 2 + wh] = pd[wh][wr];
    }
}

// ---------------- fused aggregations (wave-per-node, sync-free) ----------------

__global__ __launch_bounds__(256) void k_agg1_csr(const int* __restrict__ rowptr,
        const int* __restrict__ eidx, const float* __restrict__ s1,
        const short* __restrict__ h1b, const float* __restrict__ b1,
        short* __restrict__ out1b) {
    int wave = threadIdx.x >> 6;
    int l = threadIdx.x & 63;
    int n = blockIdx.x * 4 + wave;           // grid 12500 -> exact
    int beg = rowptr[n];
    int deg = rowptr[n + 1] - beg;
    int hh = l & 3;
    float sd_hh = s1[n * 8 + 4 + hh];
    float mloc = -1e30f;
    for (int i = (l >> 2); i < deg; i += 16)
        mloc = fmaxf(mloc, leaky(s1[eidx[beg + i] * 8 + hh] + sd_hh));
    #pragma unroll
    for (int off = 4; off <= 32; off <<= 1)
        mloc = fmaxf(mloc, __shfl_xor(mloc, off));
    int h = l >> 4;
    float m = __shfl(mloc, h);
    float sd = s1[n * 8 + 4 + h];
    float4 acc = make_float4(0.f, 0.f, 0.f, 0.f);
    float z = 0.f;
    for (int i = 0; i < deg; ++i) {
        int src = eidx[beg + i];
        float e = __expf(leaky(s1[src * 8 + h] + sd) - m);
        z += e;
        uint2 v = *(const uint2*)(h1b + src * 256 + l * 4);
        acc.x += e * bflo(v.x); acc.y += e * bfhi(v.x);
        acc.z += e * bflo(v.y); acc.w += e * bfhi(v.y);
    }
    float inv = 1.f / (z + EPS);
    float4 bb = *(const float4*)(b1 + l * 4);
    float4 o;
    o.x = acc.x * inv + bb.x; o.y = acc.y * inv + bb.y;
    o.z = acc.z * inv + bb.z; o.w = acc.w * inv + bb.w;
    o.x = o.x > 0.f ? o.x : __expf(o.x) - 1.f;
    o.y = o.y > 0.f ? o.y : __expf(o.y) - 1.f;
    o.z = o.z > 0.f ? o.z : __expf(o.z) - 1.f;
    o.w = o.w > 0.f ? o.w : __expf(o.w) - 1.f;
    uint2 w;
    w.x = bfpack(f2bf(o.x), f2bf(o.y));
    w.y = bfpack(f2bf(o.z), f2bf(o.w));
    *(uint2*)(out1b + n * 256 + l * 4) = w;
}

__global__ __launch_bounds__(256) void k_agg2_csr(const int* __restrict__ rowptr,
        const int* __restrict__ eidx, const float* __restrict__ s2,
        const short* __restrict__ h2b, const float* __restrict__ b2,
        const float* __restrict__ Wfc, const float* __restrict__ bfc,
        float* __restrict__ out) {
    int wave = threadIdx.x >> 6;
    int l = threadIdx.x & 63;
    int n = blockIdx.x * 4 + wave;           // grid 12500 -> exact
    int beg = rowptr[n];
    int deg = rowptr[n + 1] - beg;
    int hh = l & 1;
    float sd_hh = s2[n * 4 + 2 + hh];
    float mloc = -1e30f;
    for (int i = (l >> 1); i < deg; i += 32)
        mloc = fmaxf(mloc, leaky(s2[eidx[beg + i] * 4 + hh] + sd_hh));
    #pragma unroll
    for (int off = 2; off <= 32; off <<= 1)
        mloc = fmaxf(mloc, __shfl_xor(mloc, off));
    int h = l >> 5;
    float m = __shfl(mloc, h);
    float sd = s2[n * 4 + 2 + h];
    float2 acc = make_float2(0.f, 0.f);
    float z = 0.f;
    for (int i = 0; i < deg; ++i) {
        int src = eidx[beg + i];
        float e = __expf(leaky(s2[src * 4 + h] + sd) - m);
        z += e;
        unsigned v = *(const unsigned*)(h2b + src * 128 + l * 2);
        acc.x += e * bflo(v); acc.y += e * bfhi(v);
    }
    float inv = 1.f / (z + EPS);
    float v0 = acc.x * inv + b2[l * 2];
    float v1 = acc.y * inv + b2[l * 2 + 1];
    v0 = v0 > 0.f ? v0 : __expf(v0) - 1.f;
    v1 = v1 > 0.f ? v1 : __expf(v1) - 1.f;
    float p = v0 * Wfc[l * 2] + v1 * Wfc[l * 2 + 1];
    #pragma unroll
    for (int off = 1; off <= 32; off <<= 1) p += __shfl_xor(p, off);
    if (l == 0) out[n] = 1.f / (1.f + __expf(-(p + bfc[0])));
}

extern "C" void kernel_launch(void* const* d_in, const int* in_sizes, int n_in,
                              void* d_out, int out_size, void* d_ws, size_t ws_size,
                              hipStream_t stream) {
    const float* x   = (const float*)d_in[0];
    const int*   ei  = (const int*)d_in[1];
    const float* W1  = (const float*)d_in[2];
    const float* as1 = (const float*)d_in[3];
    const float* ad1 = (const float*)d_in[4];
    const float* b1  = (const float*)d_in[5];
    const float* W2  = (const float*)d_in[6];
    const float* as2 = (const float*)d_in[7];
    const float* ad2 = (const float*)d_in[8];
    const float* b2  = (const float*)d_in[9];
    const float* Wfc = (const float*)d_in[10];
    const float* bfc = (const float*)d_in[11];
    float* out = (float*)d_out;

    float* f = (float*)d_ws;
    short* h1b   = (short*)f;                    // N*256 bf16 (6.4M floats)
    short* out1b = (short*)(f + 6400000);        // N*256 bf16
    short* h2b   = (short*)(f + 12800000);       // N*128 bf16
    short* xb    = (short*)(f + 16000000);       // N*32 bf16
    short* W1bT  = (short*)(f + 16800000);       // 8192 bf16
    short* W2bT  = (short*)(f + 16810000);       // 32768 bf16
    float* s1    = f + 16830000;                 // N*8
    float* s2    = f + 17230000;                 // N*4
    int*   rowptr= (int*)(f + 17430000);         // N+1
    int*   cursor= (int*)(f + 17490000);         // N
    int*   deg   = (int*)(f + 17550000);         // N
    int*   eidx  = (int*)(f + 17610000);         // E_TOT
    int*   bsum  = (int*)(f + 17960000);         // 256
    int*   bofs  = (int*)(f + 17961000);         // 256

    // CSR build
    hipMemsetAsync(deg, 0, (size_t)N_NODES * 4, stream);
    k_hist<<<(E_TOT + 255) / 256, 256, 0, stream>>>(ei, deg);
    k_blocksum<<<SCAN_BLOCKS, 256, 0, stream>>>(deg, bsum);
    k_scanb<<<1, 256, 0, stream>>>(bsum, bofs);
    k_rowptr<<<SCAN_BLOCKS, 256, 0, stream>>>(deg, bofs, rowptr, cursor);
    k_scatter<<<(E_TOT + 255) / 256, 256, 0, stream>>>(ei, cursor, eidx);

    // bf16 prep
    k_prep_x<<<6250, 256, 0, stream>>>(x, xb);
    k_prep_w<<<128, 256, 0, stream>>>(W1, W2, W1bT, W2bT);

    // layer 1
    k_gemm1<<<782, 256, 0, stream>>>(xb, W1bT, as1, ad1, h1b, s1);
    k_agg1_csr<<<12500, 256, 0, stream>>>(rowptr, eidx, s1, h1b, b1, out1b);

    // layer 2 (+ final FC + sigmoid fused)
    k_gemm2<<<782, 256, 0, stream>>>(out1b, W2bT, as2, ad2, h2b, s2);
    k_agg2_csr<<<12500, 256, 0, stream>>>(rowptr, eidx, s2, h2b, b2, Wfc, bfc, out);
}

// Round 8
// 254.987 us; speedup vs baseline: 3.8868x; 1.1763x over previous
//
#include <hip/hip_runtime.h>
#include <math.h>

#define N_NODES 50000
#define E_EDGES 300000
#define E_TOT   350000   // E + N self-loops
#define NEG 0.2f
#define EPS 1e-16f
#define SCAN_BLOCKS 196  // 196*256 = 50176 >= 50000

typedef __attribute__((ext_vector_type(8))) short bf16x8;
typedef __attribute__((ext_vector_type(4))) float f32x4;

__device__ __forceinline__ float leaky(float x) { return x > 0.f ? x : NEG * x; }
// fp32 -> bf16 (RNE, finite inputs)
__device__ __forceinline__ short f2bf(float v) {
    unsigned u = __float_as_uint(v);
    u += 0x7fffu + ((u >> 16) & 1u);
    return (short)(u >> 16);
}
__device__ __forceinline__ float bflo(unsigned u) { return __uint_as_float(u << 16); }
__device__ __forceinline__ float bfhi(unsigned u) { return __uint_as_float(u & 0xffff0000u); }
__device__ __forceinline__ unsigned bfpack(short a, short b) {
    return (unsigned)(unsigned short)a | ((unsigned)(unsigned short)b << 16);
}

// ---------------- CSR construction ----------------

__global__ __launch_bounds__(256) void k_hist(const int* __restrict__ ei,
        int* __restrict__ deg) {
    int e = blockIdx.x * 256 + threadIdx.x;
    if (e >= E_TOT) return;
    int d = (e < E_EDGES) ? ei[E_EDGES + e] : (e - E_EDGES);
    atomicAdd(&deg[d], 1);
}

__global__ __launch_bounds__(256) void k_blocksum(const int* __restrict__ deg,
        int* __restrict__ bsum) {
    int t = threadIdx.x;
    int idx = blockIdx.x * 256 + t;
    int v = (idx < N_NODES) ? deg[idx] : 0;
    #pragma unroll
    for (int off = 32; off > 0; off >>= 1) v += __shfl_down(v, off);
    __shared__ int ws[4];
    if ((t & 63) == 0) ws[t >> 6] = v;
    __syncthreads();
    if (t == 0) bsum[blockIdx.x] = ws[0] + ws[1] + ws[2] + ws[3];
}

__global__ __launch_bounds__(256) void k_scanb(const int* __restrict__ bsum,
        int* __restrict__ bofs) {
    __shared__ int sh[256];
    int t = threadIdx.x;
    sh[t] = (t < SCAN_BLOCKS) ? bsum[t] : 0;
    __syncthreads();
    for (int s = 1; s < 256; s <<= 1) {
        int v = (t >= s) ? sh[t - s] : 0;
        __syncthreads();
        sh[t] += v;
        __syncthreads();
    }
    bofs[t] = (t == 0) ? 0 : sh[t - 1];
}

__global__ __launch_bounds__(256) void k_rowptr(const int* __restrict__ deg,
        const int* __restrict__ bofs, int* __restrict__ rowptr,
        int* __restrict__ cursor) {
    __shared__ int sh[256];
    int t = threadIdx.x;
    int idx = blockIdx.x * 256 + t;
    int v = (idx < N_NODES) ? deg[idx] : 0;
    sh[t] = v;
    __syncthreads();
    for (int s = 1; s < 256; s <<= 1) {
        int u = (t >= s) ? sh[t - s] : 0;
        __syncthreads();
        sh[t] += u;
        __syncthreads();
    }
    int excl = sh[t] - v + bofs[blockIdx.x];
    if (idx < N_NODES) { rowptr[idx] = excl; cursor[idx] = excl; }
    if (idx == N_NODES) rowptr[N_NODES] = E_TOT;
}

__global__ __launch_bounds__(256) void k_scatter(const int* __restrict__ ei,
        int* __restrict__ cursor, int* __restrict__ eidx) {
    int e = blockIdx.x * 256 + threadIdx.x;
    if (e >= E_TOT) return;
    int s = (e < E_EDGES) ? ei[e] : (e - E_EDGES);
    int d = (e < E_EDGES) ? ei[E_EDGES + e] : (e - E_EDGES);
    int pos = atomicAdd(&cursor[d], 1);
    eidx[pos] = s;
}

// ---------------- bf16 prep (x pad/convert + both weight transposes) -------

__global__ __launch_bounds__(256) void k_prep(const float* __restrict__ x,
        const float* __restrict__ W1, const float* __restrict__ W2,
        short* __restrict__ xb, short* __restrict__ W1bT,
        short* __restrict__ W2bT) {
    int b = blockIdx.x;
    if (b < 6250) {                               // xb[N,32] zero-padded bf16
        int n = b * 8 + (threadIdx.x >> 5);
        int c = threadIdx.x & 31;
        float v = (c < 27) ? x[n * 27 + c] : 0.f;
        xb[n * 32 + c] = f2bf(v);
    } else {                                      // 128 blocks of weight prep
        int t = (b - 6250) * 256 + threadIdx.x;   // 0..32767
        if (t < 256 * 32) {
            int n = t >> 5, k = t & 31;
            W1bT[t] = f2bf(k < 27 ? W1[k * 256 + n] : 0.f);
        }
        {
            int n = t >> 8, k = t & 255;
            W2bT[t] = f2bf(W2[k * 128 + n]);
        }
    }
}

// ---------------- MFMA GEMMs (no LDS, no barriers) ----------------

// h1[N,256] = xb @ W1; one wave = 16 rows; 16 col-tiles; K=32 (one MFMA each).
__global__ __launch_bounds__(256) void k_gemm1(const short* __restrict__ xb,
        const short* __restrict__ W1bT, const float* __restrict__ as1,
        const float* __restrict__ ad1, short* __restrict__ h1b,
        float* __restrict__ s1) {
    int wave = threadIdx.x >> 6, l = threadIdx.x & 63;
    int m0 = (blockIdx.x * 4 + wave) * 16;
    if (m0 >= N_NODES) return;
    int lane16 = l & 15, quad = l >> 4;
    bf16x8 a = *(const bf16x8*)(xb + (m0 + lane16) * 32 + quad * 8);
    f32x4 acc[16];
    f32x4 z4 = {0.f, 0.f, 0.f, 0.f};
    #pragma unroll
    for (int nt = 0; nt < 16; ++nt) {
        bf16x8 b = *(const bf16x8*)(W1bT + (nt * 16 + lane16) * 32 + quad * 8);
        acc[nt] = __builtin_amdgcn_mfma_f32_16x16x32_bf16(a, b, z4, 0, 0, 0);
    }
    #pragma unroll
    for (int nt = 0; nt < 16; ++nt)
        #pragma unroll
        for (int r = 0; r < 4; ++r)
            h1b[(m0 + quad * 4 + r) * 256 + nt * 16 + lane16] = f2bf(acc[nt][r]);
    float ps[4][4], pd[4][4];
    #pragma unroll
    for (int h = 0; h < 4; ++h)
        #pragma unroll
        for (int r = 0; r < 4; ++r) { ps[h][r] = 0.f; pd[h][r] = 0.f; }
    #pragma unroll
    for (int nt = 0; nt < 16; ++nt) {
        int col = nt * 16 + lane16;
        float a_s = as1[col], a_d = ad1[col];
        int h = nt >> 2;
        #pragma unroll
        for (int r = 0; r < 4; ++r) {
            ps[h][r] += acc[nt][r] * a_s;
            pd[h][r] += acc[nt][r] * a_d;
        }
    }
    #pragma unroll
    for (int off = 1; off <= 8; off <<= 1)
        #pragma unroll
        for (int h = 0; h < 4; ++h)
            #pragma unroll
            for (int r = 0; r < 4; ++r) {
                ps[h][r] += __shfl_xor(ps[h][r], off);
                pd[h][r] += __shfl_xor(pd[h][r], off);
            }
    int wh = lane16 >> 2, wr = lane16 & 3;
    int wn = m0 + quad * 4 + wr;
    s1[wn * 8 + wh] = ps[wh][wr];
    s1[wn * 8 + 4 + wh] = pd[wh][wr];
}

// h2[N,128] = out1b @ W2; wave = 16 rows; 8 col-tiles; K-loop 8x32.
__global__ __launch_bounds__(256) void k_gemm2(const short* __restrict__ out1b,
        const short* __restrict__ W2bT, const float* __restrict__ as2,
        const float* __restrict__ ad2, short* __restrict__ h2b,
        float* __restrict__ s2) {
    int wave = threadIdx.x >> 6, l = threadIdx.x & 63;
    int m0 = (blockIdx.x * 4 + wave) * 16;
    if (m0 >= N_NODES) return;
    int lane16 = l & 15, quad = l >> 4;
    f32x4 acc[8];
    f32x4 z4 = {0.f, 0.f, 0.f, 0.f};
    #pragma unroll
    for (int nt = 0; nt < 8; ++nt) acc[nt] = z4;
    for (int k0 = 0; k0 < 256; k0 += 32) {
        bf16x8 a = *(const bf16x8*)(out1b + (m0 + lane16) * 256 + k0 + quad * 8);
        #pragma unroll
        for (int nt = 0; nt < 8; ++nt) {
            bf16x8 b = *(const bf16x8*)(W2bT + (nt * 16 + lane16) * 256 + k0 + quad * 8);
            acc[nt] = __builtin_amdgcn_mfma_f32_16x16x32_bf16(a, b, acc[nt], 0, 0, 0);
        }
    }
    #pragma unroll
    for (int nt = 0; nt < 8; ++nt)
        #pragma unroll
        for (int r = 0; r < 4; ++r)
            h2b[(m0 + quad * 4 + r) * 128 + nt * 16 + lane16] = f2bf(acc[nt][r]);
    float ps[2][4], pd[2][4];
    #pragma unroll
    for (int h = 0; h < 2; ++h)
        #pragma unroll
        for (int r = 0; r < 4; ++r) { ps[h][r] = 0.f; pd[h][r] = 0.f; }
    #pragma unroll
    for (int nt = 0; nt < 8; ++nt) {
        int col = nt * 16 + lane16;
        float a_s = as2[col], a_d = ad2[col];
        int h = nt >> 2;
        #pragma unroll
        for (int r = 0; r < 4; ++r) {
            ps[h][r] += acc[nt][r] * a_s;
            pd[h][r] += acc[nt][r] * a_d;
        }
    }
    #pragma unroll
    for (int off = 1; off <= 8; off <<= 1)
        #pragma unroll
        for (int h = 0; h < 2; ++h)
            #pragma unroll
            for (int r = 0; r < 4; ++r) {
                ps[h][r] += __shfl_xor(ps[h][r], off);
                pd[h][r] += __shfl_xor(pd[h][r], off);
            }
    if (lane16 < 8) {
        int wh = lane16 >> 2, wr = lane16 & 3;
        int wn = m0 + quad * 4 + wr;
        s2[wn * 4 + wh] = ps[wh][wr];
        s2[wn * 4 + 2 + wh] = pd[wh][wr];
    }
}

// -------- fused aggregations: wave-per-node, no-max softmax, 4x unrolled ----

__global__ __launch_bounds__(256) void k_agg1_csr(const int* __restrict__ rowptr,
        const int* __restrict__ eidx, const float* __restrict__ s1,
        const short* __restrict__ h1b, const float* __restrict__ b1,
        short* __restrict__ out1b) {
    int wave = threadIdx.x >> 6;
    int l = threadIdx.x & 63;
    int n = blockIdx.x * 4 + wave;           // grid 12500 -> exact
    int beg = rowptr[n];
    int deg = rowptr[n + 1] - beg;
    int h = l >> 4;
    float sd = s1[n * 8 + 4 + h];
    float4 acc = make_float4(0.f, 0.f, 0.f, 0.f);
    float z = 0.f;
    int i = 0;
    for (; i + 4 <= deg; i += 4) {
        int a0 = eidx[beg + i], a1 = eidx[beg + i + 1];
        int a2 = eidx[beg + i + 2], a3 = eidx[beg + i + 3];
        float e0 = __expf(leaky(s1[a0 * 8 + h] + sd));
        float e1 = __expf(leaky(s1[a1 * 8 + h] + sd));
        float e2 = __expf(leaky(s1[a2 * 8 + h] + sd));
        float e3 = __expf(leaky(s1[a3 * 8 + h] + sd));
        uint2 v0 = *(const uint2*)(h1b + a0 * 256 + l * 4);
        uint2 v1 = *(const uint2*)(h1b + a1 * 256 + l * 4);
        uint2 v2 = *(const uint2*)(h1b + a2 * 256 + l * 4);
        uint2 v3 = *(const uint2*)(h1b + a3 * 256 + l * 4);
        z += e0 + e1 + e2 + e3;
        acc.x += e0 * bflo(v0.x) + e1 * bflo(v1.x) + e2 * bflo(v2.x) + e3 * bflo(v3.x);
        acc.y += e0 * bfhi(v0.x) + e1 * bfhi(v1.x) + e2 * bfhi(v2.x) + e3 * bfhi(v3.x);
        acc.z += e0 * bflo(v0.y) + e1 * bflo(v1.y) + e2 * bflo(v2.y) + e3 * bflo(v3.y);
        acc.w += e0 * bfhi(v0.y) + e1 * bfhi(v1.y) + e2 * bfhi(v2.y) + e3 * bfhi(v3.y);
    }
    for (; i < deg; ++i) {
        int a0 = eidx[beg + i];
        float e0 = __expf(leaky(s1[a0 * 8 + h] + sd));
        uint2 v0 = *(const uint2*)(h1b + a0 * 256 + l * 4);
        z += e0;
        acc.x += e0 * bflo(v0.x); acc.y += e0 * bfhi(v0.x);
        acc.z += e0 * bflo(v0.y); acc.w += e0 * bfhi(v0.y);
    }
    float inv = 1.f / (z + EPS);
    float4 bb = *(const float4*)(b1 + l * 4);
    float4 o;
    o.x = acc.x * inv + bb.x; o.y = acc.y * inv + bb.y;
    o.z = acc.z * inv + bb.z; o.w = acc.w * inv + bb.w;
    o.x = o.x > 0.f ? o.x : __expf(o.x) - 1.f;
    o.y = o.y > 0.f ? o.y : __expf(o.y) - 1.f;
    o.z = o.z > 0.f ? o.z : __expf(o.z) - 1.f;
    o.w = o.w > 0.f ? o.w : __expf(o.w) - 1.f;
    uint2 w;
    w.x = bfpack(f2bf(o.x), f2bf(o.y));
    w.y = bfpack(f2bf(o.z), f2bf(o.w));
    *(uint2*)(out1b + n * 256 + l * 4) = w;
}

__global__ __launch_bounds__(256) void k_agg2_csr(const int* __restrict__ rowptr,
        const int* __restrict__ eidx, const float* __restrict__ s2,
        const short* __restrict__ h2b, const float* __restrict__ b2,
        const float* __restrict__ Wfc, const float* __restrict__ bfc,
        float* __restrict__ out) {
    int wave = threadIdx.x >> 6;
    int l = threadIdx.x & 63;
    int n = blockIdx.x * 4 + wave;           // grid 12500 -> exact
    int beg = rowptr[n];
    int deg = rowptr[n + 1] - beg;
    int h = l >> 5;
    float sd = s2[n * 4 + 2 + h];
    float2 acc = make_float2(0.f, 0.f);
    float z = 0.f;
    int i = 0;
    for (; i + 4 <= deg; i += 4) {
        int a0 = eidx[beg + i], a1 = eidx[beg + i + 1];
        int a2 = eidx[beg + i + 2], a3 = eidx[beg + i + 3];
        float e0 = __expf(leaky(s2[a0 * 4 + h] + sd));
        float e1 = __expf(leaky(s2[a1 * 4 + h] + sd));
        float e2 = __expf(leaky(s2[a2 * 4 + h] + sd));
        float e3 = __expf(leaky(s2[a3 * 4 + h] + sd));
        unsigned v0 = *(const unsigned*)(h2b + a0 * 128 + l * 2);
        unsigned v1 = *(const unsigned*)(h2b + a1 * 128 + l * 2);
        unsigned v2 = *(const unsigned*)(h2b + a2 * 128 + l * 2);
        unsigned v3 = *(const unsigned*)(h2b + a3 * 128 + l * 2);
        z += e0 + e1 + e2 + e3;
        acc.x += e0 * bflo(v0) + e1 * bflo(v1) + e2 * bflo(v2) + e3 * bflo(v3);
        acc.y += e0 * bfhi(v0) + e1 * bfhi(v1) + e2 * bfhi(v2) + e3 * bfhi(v3);
    }
    for (; i < deg; ++i) {
        int a0 = eidx[beg + i];
        float e0 = __expf(leaky(s2[a0 * 4 + h] + sd));
        unsigned v0 = *(const unsigned*)(h2b + a0 * 128 + l * 2);
        z += e0;
        acc.x += e0 * bflo(v0); acc.y += e0 * bfhi(v0);
    }
    float inv = 1.f / (z + EPS);
    float v0 = acc.x * inv + b2[l * 2];
    float v1 = acc.y * inv + b2[l * 2 + 1];
    v0 = v0 > 0.f ? v0 : __expf(v0) - 1.f;
    v1 = v1 > 0.f ? v1 : __expf(v1) - 1.f;
    float p = v0 * Wfc[l * 2] + v1 * Wfc[l * 2 + 1];
    #pragma unroll
    for (int off = 1; off <= 32; off <<= 1) p += __shfl_xor(p, off);
    if (l == 0) out[n] = 1.f / (1.f + __expf(-(p + bfc[0])));
}

extern "C" void kernel_launch(void* const* d_in, const int* in_sizes, int n_in,
                              void* d_out, int out_size, void* d_ws, size_t ws_size,
                              hipStream_t stream) {
    const float* x   = (const float*)d_in[0];
    const int*   ei  = (const int*)d_in[1];
    const float* W1  = (const float*)d_in[2];
    const float* as1 = (const float*)d_in[3];
    const float* ad1 = (const float*)d_in[4];
    const float* b1  = (const float*)d_in[5];
    const float* W2  = (const float*)d_in[6];
    const float* as2 = (const float*)d_in[7];
    const float* ad2 = (const float*)d_in[8];
    const float* b2  = (const float*)d_in[9];
    const float* Wfc = (const float*)d_in[10];
    const float* bfc = (const float*)d_in[11];
    float* out = (float*)d_out;

    float* f = (float*)d_ws;
    short* h1b   = (short*)f;                    // N*256 bf16
    short* out1b = (short*)(f + 6400000);        // N*256 bf16
    short* h2b   = (short*)(f + 12800000);       // N*128 bf16
    short* xb    = (short*)(f + 16000000);       // N*32 bf16
    short* W1bT  = (short*)(f + 16800000);       // 8192 bf16
    short* W2bT  = (short*)(f + 16810000);       // 32768 bf16
    float* s1    = f + 16830000;                 // N*8
    float* s2    = f + 17230000;                 // N*4
    int*   rowptr= (int*)(f + 17430000);         // N+1
    int*   cursor= (int*)(f + 17490000);         // N
    int*   deg   = (int*)(f + 17550000);         // N
    int*   eidx  = (int*)(f + 17610000);         // E_TOT
    int*   bsum  = (int*)(f + 17960000);         // 256
    int*   bofs  = (int*)(f + 17961000);         // 256

    // CSR build
    hipMemsetAsync(deg, 0, (size_t)N_NODES * 4, stream);
    k_hist<<<(E_TOT + 255) / 256, 256, 0, stream>>>(ei, deg);
    k_blocksum<<<SCAN_BLOCKS, 256, 0, stream>>>(deg, bsum);
    k_scanb<<<1, 256, 0, stream>>>(bsum, bofs);
    k_rowptr<<<SCAN_BLOCKS, 256, 0, stream>>>(deg, bofs, rowptr, cursor);
    k_scatter<<<(E_TOT + 255) / 256, 256, 0, stream>>>(ei, cursor, eidx);

    // bf16 prep (x + weights fused)
    k_prep<<<6378, 256, 0, stream>>>(x, W1, W2, xb, W1bT, W2bT);

    // layer 1
    k_gemm1<<<782, 256, 0, stream>>>(xb, W1bT, as1, ad1, h1b, s1);
    k_agg1_csr<<<12500, 256, 0, stream>>>(rowptr, eidx, s1, h1b, b1, out1b);

    // layer 2 (+ final FC + sigmoid fused)
    k_gemm2<<<782, 256, 0, stream>>>(out1b, W2bT, as2, ad2, h2b, s2);
    k_agg2_csr<<<12500, 256, 0, stream>>>(rowptr, eidx, s2, h2b, b2, Wfc, bfc, out);
}

// Round 9
// 245.037 us; speedup vs baseline: 4.0446x; 1.0406x over previous
//
#include <hip/hip_runtime.h>
#include <math.h>

#define N_NODES 50000
#define E_EDGES 300000
#define E_TOT   350000   // E + N self-loops
#define NEG 0.2f
#define EPS 1e-16f
#define SCAN_BLOCKS 196  // 196*256 = 50176 >= 50000

typedef __attribute__((ext_vector_type(8))) short bf16x8;
typedef __attribute__((ext_vector_type(4))) float f32x4;

__device__ __forceinline__ float leaky(float x) { return x > 0.f ? x : NEG * x; }
// fp32 -> bf16 (RNE, finite inputs)
__device__ __forceinline__ short f2bf(float v) {
    unsigned u = __float_as_uint(v);
    u += 0x7fffu + ((u >> 16) & 1u);
    return (short)(u >> 16);
}
__device__ __forceinline__ float bflo(unsigned u) { return __uint_as_float(u << 16); }
__device__ __forceinline__ float bfhi(unsigned u) { return __uint_as_float(u & 0xffff0000u); }
__device__ __forceinline__ unsigned bfpack(short a, short b) {
    return (unsigned)(unsigned short)a | ((unsigned)(unsigned short)b << 16);
}

// ---------------- CSR construction ----------------

__global__ __launch_bounds__(256) void k_hist(const int* __restrict__ ei,
        int* __restrict__ deg) {
    int e = blockIdx.x * 256 + threadIdx.x;
    if (e >= E_TOT) return;
    int d = (e < E_EDGES) ? ei[E_EDGES + e] : (e - E_EDGES);
    atomicAdd(&deg[d], 1);
}

__global__ __launch_bounds__(256) void k_blocksum(const int* __restrict__ deg,
        int* __restrict__ bsum) {
    int t = threadIdx.x;
    int idx = blockIdx.x * 256 + t;
    int v = (idx < N_NODES) ? deg[idx] : 0;
    #pragma unroll
    for (int off = 32; off > 0; off >>= 1) v += __shfl_down(v, off);
    __shared__ int ws[4];
    if ((t & 63) == 0) ws[t >> 6] = v;
    __syncthreads();
    if (t == 0) bsum[blockIdx.x] = ws[0] + ws[1] + ws[2] + ws[3];
}

__global__ __launch_bounds__(256) void k_scanb(const int* __restrict__ bsum,
        int* __restrict__ bofs) {
    __shared__ int sh[256];
    int t = threadIdx.x;
    sh[t] = (t < SCAN_BLOCKS) ? bsum[t] : 0;
    __syncthreads();
    for (int s = 1; s < 256; s <<= 1) {
        int v = (t >= s) ? sh[t - s] : 0;
        __syncthreads();
        sh[t] += v;
        __syncthreads();
    }
    bofs[t] = (t == 0) ? 0 : sh[t - 1];
}

__global__ __launch_bounds__(256) void k_rowptr(const int* __restrict__ deg,
        const int* __restrict__ bofs, int* __restrict__ rowptr,
        int* __restrict__ cursor) {
    __shared__ int sh[256];
    int t = threadIdx.x;
    int idx = blockIdx.x * 256 + t;
    int v = (idx < N_NODES) ? deg[idx] : 0;
    sh[t] = v;
    __syncthreads();
    for (int s = 1; s < 256; s <<= 1) {
        int u = (t >= s) ? sh[t - s] : 0;
        __syncthreads();
        sh[t] += u;
        __syncthreads();
    }
    int excl = sh[t] - v + bofs[blockIdx.x];
    if (idx < N_NODES) { rowptr[idx] = excl; cursor[idx] = excl; }
    if (idx == N_NODES) rowptr[N_NODES] = E_TOT;
}

__global__ __launch_bounds__(256) void k_scatter(const int* __restrict__ ei,
        int* __restrict__ cursor, int* __restrict__ eidx) {
    int e = blockIdx.x * 256 + threadIdx.x;
    if (e >= E_TOT) return;
    int s = (e < E_EDGES) ? ei[e] : (e - E_EDGES);
    int d = (e < E_EDGES) ? ei[E_EDGES + e] : (e - E_EDGES);
    int pos = atomicAdd(&cursor[d], 1);
    eidx[pos] = s;
}

// ---------------- bf16 prep (x pad/convert + both weight transposes) -------

__global__ __launch_bounds__(256) void k_prep(const float* __restrict__ x,
        const float* __restrict__ W1, const float* __restrict__ W2,
        short* __restrict__ xb, short* __restrict__ W1bT,
        short* __restrict__ W2bT) {
    int b = blockIdx.x;
    if (b < 6250) {                               // xb[N,32] zero-padded bf16
        int n = b * 8 + (threadIdx.x >> 5);
        int c = threadIdx.x & 31;
        float v = (c < 27) ? x[n * 27 + c] : 0.f;
        xb[n * 32 + c] = f2bf(v);
    } else {                                      // 128 blocks of weight prep
        int t = (b - 6250) * 256 + threadIdx.x;   // 0..32767
        if (t < 256 * 32) {
            int n = t >> 5, k = t & 31;
            W1bT[t] = f2bf(k < 27 ? W1[k * 256 + n] : 0.f);
        }
        {
            int n = t >> 8, k = t & 255;
            W2bT[t] = f2bf(W2[k * 128 + n]);
        }
    }
}

// ---------------- MFMA GEMMs (no LDS, no barriers) ----------------
// Col-split: each wave = 16 rows x half the columns -> 2x waves in flight.

// h1[N,256] = xb @ W1. Block: 32 rows; wave (w>>1)=row-half, (w&1)=col-half.
__global__ __launch_bounds__(256) void k_gemm1(const short* __restrict__ xb,
        const short* __restrict__ W1bT, const float* __restrict__ as1,
        const float* __restrict__ ad1, short* __restrict__ h1b,
        float* __restrict__ s1) {
    int wave = threadIdx.x >> 6, l = threadIdx.x & 63;
    int m0 = (blockIdx.x * 2 + (wave >> 1)) * 16;
    if (m0 >= N_NODES) return;
    int cg2 = wave & 1;              // cols cg2*128..+128 = heads cg2*2, cg2*2+1
    int lane16 = l & 15, quad = l >> 4;
    bf16x8 a = *(const bf16x8*)(xb + (m0 + lane16) * 32 + quad * 8);
    f32x4 acc[8];
    f32x4 z4 = {0.f, 0.f, 0.f, 0.f};
    #pragma unroll
    for (int j = 0; j < 8; ++j) {
        int nt = cg2 * 8 + j;
        bf16x8 b = *(const bf16x8*)(W1bT + (nt * 16 + lane16) * 32 + quad * 8);
        acc[j] = __builtin_amdgcn_mfma_f32_16x16x32_bf16(a, b, z4, 0, 0, 0);
    }
    #pragma unroll
    for (int j = 0; j < 8; ++j) {
        int col = (cg2 * 8 + j) * 16 + lane16;
        #pragma unroll
        for (int r = 0; r < 4; ++r)
            h1b[(m0 + quad * 4 + r) * 256 + col] = f2bf(acc[j][r]);
    }
    float ps[2][4], pd[2][4];        // head-local (2 heads per col-half)
    #pragma unroll
    for (int hl = 0; hl < 2; ++hl)
        #pragma unroll
        for (int r = 0; r < 4; ++r) { ps[hl][r] = 0.f; pd[hl][r] = 0.f; }
    #pragma unroll
    for (int j = 0; j < 8; ++j) {
        int col = (cg2 * 8 + j) * 16 + lane16;
        float a_s = as1[col], a_d = ad1[col];
        int hl = j >> 2;
        #pragma unroll
        for (int r = 0; r < 4; ++r) {
            ps[hl][r] += acc[j][r] * a_s;
            pd[hl][r] += acc[j][r] * a_d;
        }
    }
    #pragma unroll
    for (int off = 1; off <= 8; off <<= 1)
        #pragma unroll
        for (int hl = 0; hl < 2; ++hl)
            #pragma unroll
            for (int r = 0; r < 4; ++r) {
                ps[hl][r] += __shfl_xor(ps[hl][r], off);
                pd[hl][r] += __shfl_xor(pd[hl][r], off);
            }
    if (lane16 < 8) {
        int hl = lane16 >> 2, wr = lane16 & 3;
        int wn = m0 + quad * 4 + wr;
        s1[wn * 8 + cg2 * 2 + hl] = ps[hl][wr];
        s1[wn * 8 + 4 + cg2 * 2 + hl] = pd[hl][wr];
    }
}

// h2[N,128] = out1b @ W2. Block: 32 rows; wave (w>>1)=row-half, (w&1)=col-half.
// Col-half == exactly one head -> epilogue reduction stays intra-wave.
__global__ __launch_bounds__(256) void k_gemm2(const short* __restrict__ out1b,
        const short* __restrict__ W2bT, const float* __restrict__ as2,
        const float* __restrict__ ad2, short* __restrict__ h2b,
        float* __restrict__ s2) {
    int wave = threadIdx.x >> 6, l = threadIdx.x & 63;
    int m0 = (blockIdx.x * 2 + (wave >> 1)) * 16;
    if (m0 >= N_NODES) return;
    int cg2 = wave & 1;              // cols cg2*64..+64 = head cg2
    int lane16 = l & 15, quad = l >> 4;
    f32x4 acc[4];
    f32x4 z4 = {0.f, 0.f, 0.f, 0.f};
    #pragma unroll
    for (int j = 0; j < 4; ++j) acc[j] = z4;
    for (int k0 = 0; k0 < 256; k0 += 32) {
        bf16x8 a = *(const bf16x8*)(out1b + (m0 + lane16) * 256 + k0 + quad * 8);
        #pragma unroll
        for (int j = 0; j < 4; ++j) {
            int nt = cg2 * 4 + j;
            bf16x8 b = *(const bf16x8*)(W2bT + (nt * 16 + lane16) * 256 + k0 + quad * 8);
            acc[j] = __builtin_amdgcn_mfma_f32_16x16x32_bf16(a, b, acc[j], 0, 0, 0);
        }
    }
    #pragma unroll
    for (int j = 0; j < 4; ++j) {
        int col = (cg2 * 4 + j) * 16 + lane16;
        #pragma unroll
        for (int r = 0; r < 4; ++r)
            h2b[(m0 + quad * 4 + r) * 128 + col] = f2bf(acc[j][r]);
    }
    float ps[4], pd[4];
    #pragma unroll
    for (int r = 0; r < 4; ++r) { ps[r] = 0.f; pd[r] = 0.f; }
    #pragma unroll
    for (int j = 0; j < 4; ++j) {
        int col = (cg2 * 4 + j) * 16 + lane16;
        float a_s = as2[col], a_d = ad2[col];
        #pragma unroll
        for (int r = 0; r < 4; ++r) {
            ps[r] += acc[j][r] * a_s;
            pd[r] += acc[j][r] * a_d;
        }
    }
    #pragma unroll
    for (int off = 1; off <= 8; off <<= 1)
        #pragma unroll
        for (int r = 0; r < 4; ++r) {
            ps[r] += __shfl_xor(ps[r], off);
            pd[r] += __shfl_xor(pd[r], off);
        }
    if (lane16 < 4) {
        int wr = lane16;
        int wn = m0 + quad * 4 + wr;
        s2[wn * 4 + cg2] = ps[wr];
        s2[wn * 4 + 2 + cg2] = pd[wr];
    }
}

// -------- fused aggregations: wave-per-node, no-max softmax, 4x unrolled ----

__global__ __launch_bounds__(256) void k_agg1_csr(const int* __restrict__ rowptr,
        const int* __restrict__ eidx, const float* __restrict__ s1,
        const short* __restrict__ h1b, const float* __restrict__ b1,
        short* __restrict__ out1b) {
    int wave = threadIdx.x >> 6;
    int l = threadIdx.x & 63;
    int n = blockIdx.x * 4 + wave;           // grid 12500 -> exact
    int beg = rowptr[n];
    int deg = rowptr[n + 1] - beg;
    int h = l >> 4;
    float sd = s1[n * 8 + 4 + h];
    float4 acc = make_float4(0.f, 0.f, 0.f, 0.f);
    float z = 0.f;
    int i = 0;
    for (; i + 4 <= deg; i += 4) {
        int a0 = eidx[beg + i], a1 = eidx[beg + i + 1];
        int a2 = eidx[beg + i + 2], a3 = eidx[beg + i + 3];
        float e0 = __expf(leaky(s1[a0 * 8 + h] + sd));
        float e1 = __expf(leaky(s1[a1 * 8 + h] + sd));
        float e2 = __expf(leaky(s1[a2 * 8 + h] + sd));
        float e3 = __expf(leaky(s1[a3 * 8 + h] + sd));
        uint2 v0 = *(const uint2*)(h1b + a0 * 256 + l * 4);
        uint2 v1 = *(const uint2*)(h1b + a1 * 256 + l * 4);
        uint2 v2 = *(const uint2*)(h1b + a2 * 256 + l * 4);
        uint2 v3 = *(const uint2*)(h1b + a3 * 256 + l * 4);
        z += e0 + e1 + e2 + e3;
        acc.x += e0 * bflo(v0.x) + e1 * bflo(v1.x) + e2 * bflo(v2.x) + e3 * bflo(v3.x);
        acc.y += e0 * bfhi(v0.x) + e1 * bfhi(v1.x) + e2 * bfhi(v2.x) + e3 * bfhi(v3.x);
        acc.z += e0 * bflo(v0.y) + e1 * bflo(v1.y) + e2 * bflo(v2.y) + e3 * bflo(v3.y);
        acc.w += e0 * bfhi(v0.y) + e1 * bfhi(v1.y) + e2 * bfhi(v2.y) + e3 * bfhi(v3.y);
    }
    for (; i < deg; ++i) {
        int a0 = eidx[beg + i];
        float e0 = __expf(leaky(s1[a0 * 8 + h] + sd));
        uint2 v0 = *(const uint2*)(h1b + a0 * 256 + l * 4);
        z += e0;
        acc.x += e0 * bflo(v0.x); acc.y += e0 * bfhi(v0.x);
        acc.z += e0 * bflo(v0.y); acc.w += e0 * bfhi(v0.y);
    }
    float inv = 1.f / (z + EPS);
    float4 bb = *(const float4*)(b1 + l * 4);
    float4 o;
    o.x = acc.x * inv + bb.x; o.y = acc.y * inv + bb.y;
    o.z = acc.z * inv + bb.z; o.w = acc.w * inv + bb.w;
    o.x = o.x > 0.f ? o.x : __expf(o.x) - 1.f;
    o.y = o.y > 0.f ? o.y : __expf(o.y) - 1.f;
    o.z = o.z > 0.f ? o.z : __expf(o.z) - 1.f;
    o.w = o.w > 0.f ? o.w : __expf(o.w) - 1.f;
    uint2 w;
    w.x = bfpack(f2bf(o.x), f2bf(o.y));
    w.y = bfpack(f2bf(o.z), f2bf(o.w));
    *(uint2*)(out1b + n * 256 + l * 4) = w;
}

__global__ __launch_bounds__(256) void k_agg2_csr(const int* __restrict__ rowptr,
        const int* __restrict__ eidx, const float* __restrict__ s2,
        const short* __restrict__ h2b, const float* __restrict__ b2,
        const float* __restrict__ Wfc, const float* __restrict__ bfc,
        float* __restrict__ out) {
    int wave = threadIdx.x >> 6;
    int l = threadIdx.x & 63;
    int n = blockIdx.x * 4 + wave;           // grid 12500 -> exact
    int beg = rowptr[n];
    int deg = rowptr[n + 1] - beg;
    int h = l >> 5;
    float sd = s2[n * 4 + 2 + h];
    float2 acc = make_float2(0.f, 0.f);
    float z = 0.f;
    int i = 0;
    for (; i + 4 <= deg; i += 4) {
        int a0 = eidx[beg + i], a1 = eidx[beg + i + 1];
        int a2 = eidx[beg + i + 2], a3 = eidx[beg + i + 3];
        float e0 = __expf(leaky(s2[a0 * 4 + h] + sd));
        float e1 = __expf(leaky(s2[a1 * 4 + h] + sd));
        float e2 = __expf(leaky(s2[a2 * 4 + h] + sd));
        float e3 = __expf(leaky(s2[a3 * 4 + h] + sd));
        unsigned v0 = *(const unsigned*)(h2b + a0 * 128 + l * 2);
        unsigned v1 = *(const unsigned*)(h2b + a1 * 128 + l * 2);
        unsigned v2 = *(const unsigned*)(h2b + a2 * 128 + l * 2);
        unsigned v3 = *(const unsigned*)(h2b + a3 * 128 + l * 2);
        z += e0 + e1 + e2 + e3;
        acc.x += e0 * bflo(v0) + e1 * bflo(v1) + e2 * bflo(v2) + e3 * bflo(v3);
        acc.y += e0 * bfhi(v0) + e1 * bfhi(v1) + e2 * bfhi(v2) + e3 * bfhi(v3);
    }
    for (; i < deg; ++i) {
        int a0 = eidx[beg + i];
        float e0 = __expf(leaky(s2[a0 * 4 + h] + sd));
        unsigned v0 = *(const unsigned*)(h2b + a0 * 128 + l * 2);
        z += e0;
        acc.x += e0 * bflo(v0); acc.y += e0 * bfhi(v0);
    }
    float inv = 1.f / (z + EPS);
    float v0 = acc.x * inv + b2[l * 2];
    float v1 = acc.y * inv + b2[l * 2 + 1];
    v0 = v0 > 0.f ? v0 : __expf(v0) - 1.f;
    v1 = v1 > 0.f ? v1 : __expf(v1) - 1.f;
    float p = v0 * Wfc[l * 2] + v1 * Wfc[l * 2 + 1];
    #pragma unroll
    for (int off = 1; off <= 32; off <<= 1) p += __shfl_xor(p, off);
    if (l == 0) out[n] = 1.f / (1.f + __expf(-(p + bfc[0])));
}

extern "C" void kernel_launch(void* const* d_in, const int* in_sizes, int n_in,
                              void* d_out, int out_size, void* d_ws, size_t ws_size,
                              hipStream_t stream) {
    const float* x   = (const float*)d_in[0];
    const int*   ei  = (const int*)d_in[1];
    const float* W1  = (const float*)d_in[2];
    const float* as1 = (const float*)d_in[3];
    const float* ad1 = (const float*)d_in[4];
    const float* b1  = (const float*)d_in[5];
    const float* W2  = (const float*)d_in[6];
    const float* as2 = (const float*)d_in[7];
    const float* ad2 = (const float*)d_in[8];
    const float* b2  = (const float*)d_in[9];
    const float* Wfc = (const float*)d_in[10];
    const float* bfc = (const float*)d_in[11];
    float* out = (float*)d_out;

    float* f = (float*)d_ws;
    short* h1b   = (short*)f;                    // N*256 bf16
    short* out1b = (short*)(f + 6400000);        // N*256 bf16
    short* h2b   = (short*)(f + 12800000);       // N*128 bf16
    short* xb    = (short*)(f + 16000000);       // N*32 bf16
    short* W1bT  = (short*)(f + 16800000);       // 8192 bf16
    short* W2bT  = (short*)(f + 16810000);       // 32768 bf16
    float* s1    = f + 16830000;                 // N*8
    float* s2    = f + 17230000;                 // N*4
    int*   rowptr= (int*)(f + 17430000);         // N+1
    int*   cursor= (int*)(f + 17490000);         // N
    int*   deg   = (int*)(f + 17550000);         // N
    int*   eidx  = (int*)(f + 17610000);         // E_TOT
    int*   bsum  = (int*)(f + 17960000);         // 256
    int*   bofs  = (int*)(f + 17961000);         // 256

    // CSR build
    hipMemsetAsync(deg, 0, (size_t)N_NODES * 4, stream);
    k_hist<<<(E_TOT + 255) / 256, 256, 0, stream>>>(ei, deg);
    k_blocksum<<<SCAN_BLOCKS, 256, 0, stream>>>(deg, bsum);
    k_scanb<<<1, 256, 0, stream>>>(bsum, bofs);
    k_rowptr<<<SCAN_BLOCKS, 256, 0, stream>>>(deg, bofs, rowptr, cursor);
    k_scatter<<<(E_TOT + 255) / 256, 256, 0, stream>>>(ei, cursor, eidx);

    // bf16 prep (x + weights fused)
    k_prep<<<6378, 256, 0, stream>>>(x, W1, W2, xb, W1bT, W2bT);

    // layer 1
    k_gemm1<<<1563, 256, 0, stream>>>(xb, W1bT, as1, ad1, h1b, s1);
    k_agg1_csr<<<12500, 256, 0, stream>>>(rowptr, eidx, s1, h1b, b1, out1b);

    // layer 2 (+ final FC + sigmoid fused)
    k_gemm2<<<1563, 256, 0, stream>>>(out1b, W2bT, as2, ad2, h2b, s2);
    k_agg2_csr<<<12500, 256, 0, stream>>>(rowptr, eidx, s2, h2b, b2, Wfc, bfc, out);
}

// Round 10
// 214.769 us; speedup vs baseline: 4.6146x; 1.1409x over previous
//
#include <hip/hip_runtime.h>
#include <math.h>

#define N_NODES 50000
#define E_EDGES 300000
#define E_TOT   350000   // E + N self-loops
#define NEG 0.2f
#define EPS 1e-16f
#define SCAN_BLOCKS 196  // 196*256 = 50176 >= 50000

typedef __attribute__((ext_vector_type(8))) short bf16x8;
typedef __attribute__((ext_vector_type(4))) float f32x4;

__device__ __forceinline__ float leaky(float x) { return x > 0.f ? x : NEG * x; }
// fp32 -> bf16 (RNE, finite inputs)
__device__ __forceinline__ short f2bf(float v) {
    unsigned u = __float_as_uint(v);
    u += 0x7fffu + ((u >> 16) & 1u);
    return (short)(u >> 16);
}
__device__ __forceinline__ float bflo(unsigned u) { return __uint_as_float(u << 16); }
__device__ __forceinline__ float bfhi(unsigned u) { return __uint_as_float(u & 0xffff0000u); }

// ---------------- CSR construction ----------------

__global__ __launch_bounds__(256) void k_hist(const int* __restrict__ ei,
        int* __restrict__ deg) {
    int e = blockIdx.x * 256 + threadIdx.x;
    if (e >= E_TOT) return;
    int d = (e < E_EDGES) ? ei[E_EDGES + e] : (e - E_EDGES);
    atomicAdd(&deg[d], 1);
}

__global__ __launch_bounds__(256) void k_blocksum(const int* __restrict__ deg,
        int* __restrict__ bsum) {
    int t = threadIdx.x;
    int idx = blockIdx.x * 256 + t;
    int v = (idx < N_NODES) ? deg[idx] : 0;
    #pragma unroll
    for (int off = 32; off > 0; off >>= 1) v += __shfl_down(v, off);
    __shared__ int ws[4];
    if ((t & 63) == 0) ws[t >> 6] = v;
    __syncthreads();
    if (t == 0) bsum[blockIdx.x] = ws[0] + ws[1] + ws[2] + ws[3];
}

__global__ __launch_bounds__(256) void k_scanb(const int* __restrict__ bsum,
        int* __restrict__ bofs) {
    __shared__ int sh[256];
    int t = threadIdx.x;
    sh[t] = (t < SCAN_BLOCKS) ? bsum[t] : 0;
    __syncthreads();
    for (int s = 1; s < 256; s <<= 1) {
        int v = (t >= s) ? sh[t - s] : 0;
        __syncthreads();
        sh[t] += v;
        __syncthreads();
    }
    bofs[t] = (t == 0) ? 0 : sh[t - 1];
}

__global__ __launch_bounds__(256) void k_rowptr(const int* __restrict__ deg,
        const int* __restrict__ bofs, int* __restrict__ rowptr,
        int* __restrict__ cursor) {
    __shared__ int sh[256];
    int t = threadIdx.x;
    int idx = blockIdx.x * 256 + t;
    int v = (idx < N_NODES) ? deg[idx] : 0;
    sh[t] = v;
    __syncthreads();
    for (int s = 1; s < 256; s <<= 1) {
        int u = (t >= s) ? sh[t - s] : 0;
        __syncthreads();
        sh[t] += u;
        __syncthreads();
    }
    int excl = sh[t] - v + bofs[blockIdx.x];
    if (idx < N_NODES) { rowptr[idx] = excl; cursor[idx] = excl; }
    if (idx == N_NODES) rowptr[N_NODES] = E_TOT;
}

__global__ __launch_bounds__(256) void k_scatter(const int* __restrict__ ei,
        int* __restrict__ cursor, int* __restrict__ eidx) {
    int e = blockIdx.x * 256 + threadIdx.x;
    if (e >= E_TOT) return;
    int s = (e < E_EDGES) ? ei[e] : (e - E_EDGES);
    int d = (e < E_EDGES) ? ei[E_EDGES + e] : (e - E_EDGES);
    int pos = atomicAdd(&cursor[d], 1);
    eidx[pos] = s;
}

// ---------------- prep: wsv = W1·a vectors, W1b (padded B^T), W2bT ----------

__global__ __launch_bounds__(256) void k_prep(const float* __restrict__ W1,
        const float* __restrict__ as1, const float* __restrict__ ad1,
        const float* __restrict__ W2, float* __restrict__ wsv,
        short* __restrict__ W1b, short* __restrict__ W2bT) {
    int t = blockIdx.x * 256 + threadIdx.x;      // grid 128 -> 32768 threads
    // W2bT[col][k] = W2[k][col]
    {
        int col = t >> 8, k = t & 255;
        W2bT[t] = f2bf(W2[k * 128 + col]);
    }
    // W1b[h][col][k] = W1[k][h*64+col], k padded 27->32
    if (t < 8192) {
        int h = t >> 11, col = (t >> 5) & 63, k = t & 31;
        W1b[t] = f2bf(k < 27 ? W1[k * 256 + h * 64 + col] : 0.f);
    }
    // wsv[k][j]: j<4 -> sum_d W1[k][j*64+d]*as1[j*64+d]; j>=4 -> ad1
    if (t < 216) {
        int k = t >> 3, j = t & 7;
        const float* av = (j < 4) ? (as1 + j * 64) : (ad1 + (j - 4) * 64);
        const float* wr = W1 + k * 256 + ((j & 3) * 64);
        float s = 0.f;
        for (int d = 0; d < 64; ++d) s += wr[d] * av[d];
        wsv[k * 8 + j] = s;
    }
}

// s1[n][0..3]=src half-scores, [4..7]=dst — direct from x via wsv (27->8 GEMV)
__global__ __launch_bounds__(256) void k_s1(const float* __restrict__ x,
        const float* __restrict__ wsv, float* __restrict__ s1) {
    int idx = blockIdx.x * 256 + threadIdx.x;    // grid 1563
    if (idx >= N_NODES * 8) return;
    int n = idx >> 3, j = idx & 7;
    float s = 0.f;
    #pragma unroll
    for (int k = 0; k < 27; ++k) s += x[n * 27 + k] * wsv[k * 8 + j];
    s1[idx] = s;
}

// ---------------- fused layer-1 agg (x-space) + expand + GEMM2 ----------------
// Block = 16 nodes. Phase A: waves aggregate xagg[h][m][c] (fp32->bf16, LDS).
// Phase B: wave w = head w expands out1'[16x64] via 4 MFMAs -> elu -> LDS O.
// Phase C: wave w computes h2 col-tiles {2w,2w+1} (K=256, 16 MFMAs) + s2.
__global__ __launch_bounds__(256) void k_fused1(const int* __restrict__ rowptr,
        const int* __restrict__ eidx, const float* __restrict__ x,
        const float* __restrict__ s1, const short* __restrict__ W1b,
        const short* __restrict__ W2bT, const float* __restrict__ b1,
        const float* __restrict__ as2, const float* __restrict__ ad2,
        short* __restrict__ h2b, float* __restrict__ s2) {
    __shared__ short LDSx[4 * 16 * 32];          // [head][m][k] bf16
    __shared__ short O[16 * 264];                // out1' [m][col], padded stride
    __shared__ float P[4][2][16];                // s2 partials [wave][ps/pd][m]
    int w = threadIdx.x >> 6, l = threadIdx.x & 63;
    int n0 = blockIdx.x * 16;                    // grid 3125 -> 50000 exact
    int h5 = l >> 5, c = l & 31;                 // half-wave, channel slot
    f32x4 z4 = {0.f, 0.f, 0.f, 0.f};

    // Phase A: each wave aggregates 4 nodes (2 rounds x 2 half-waves)
    for (int r = 0; r < 2; ++r) {
        int m = w * 4 + r * 2 + h5;
        int n = n0 + m;
        int beg = rowptr[n];
        int deg = rowptr[n + 1] - beg;
        int degmax = max(deg, __shfl_xor(deg, 32));
        float4 sdv = *(const float4*)(s1 + n * 8 + 4);
        float a0 = 0.f, a1 = 0.f, a2 = 0.f, a3 = 0.f;
        float z0 = 0.f, z1 = 0.f, z2 = 0.f, z3 = 0.f;
        for (int i = 0; i < degmax; ++i) {
            bool act = i < deg;
            int src = act ? eidx[beg + i] : n;
            float4 sv = *(const float4*)(s1 + src * 8);
            float g = act ? 1.f : 0.f;
            float e0 = g * __expf(leaky(sv.x + sdv.x));
            float e1 = g * __expf(leaky(sv.y + sdv.y));
            float e2 = g * __expf(leaky(sv.z + sdv.z));
            float e3 = g * __expf(leaky(sv.w + sdv.w));
            float xv = (act && c < 27) ? x[src * 27 + c] : 0.f;
            z0 += e0; z1 += e1; z2 += e2; z3 += e3;
            a0 += e0 * xv; a1 += e1 * xv; a2 += e2 * xv; a3 += e3 * xv;
        }
        float i0 = 1.f / (z0 + EPS), i1 = 1.f / (z1 + EPS);
        float i2 = 1.f / (z2 + EPS), i3 = 1.f / (z3 + EPS);
        LDSx[0 * 512 + m * 32 + c] = f2bf(a0 * i0);
        LDSx[1 * 512 + m * 32 + c] = f2bf(a1 * i1);
        LDSx[2 * 512 + m * 32 + c] = f2bf(a2 * i2);
        LDSx[3 * 512 + m * 32 + c] = f2bf(a3 * i3);
    }
    __syncthreads();

    int lane16 = l & 15, quad = l >> 4;
    // Phase B: expand head w: [16x32] @ [32x64] -> elu -> O
    {
        bf16x8 a = *(const bf16x8*)&LDSx[w * 512 + lane16 * 32 + quad * 8];
        f32x4 cacc[4];
        #pragma unroll
        for (int nt = 0; nt < 4; ++nt) {
            bf16x8 b = *(const bf16x8*)&W1b[w * 2048 + (nt * 16 + lane16) * 32 + quad * 8];
            cacc[nt] = __builtin_amdgcn_mfma_f32_16x16x32_bf16(a, b, z4, 0, 0, 0);
        }
        #pragma unroll
        for (int nt = 0; nt < 4; ++nt) {
            int col = w * 64 + nt * 16 + lane16;
            float bb = b1[col];
            #pragma unroll
            for (int r2 = 0; r2 < 4; ++r2) {
                float v = cacc[nt][r2] + bb;
                v = v > 0.f ? v : __expf(v) - 1.f;
                O[(quad * 4 + r2) * 264 + col] = f2bf(v);
            }
        }
    }
    __syncthreads();

    // Phase C: gemm2, wave w -> h2 col-tiles {2w, 2w+1}
    f32x4 acc2[2];
    acc2[0] = z4; acc2[1] = z4;
    for (int k0 = 0; k0 < 256; k0 += 32) {
        bf16x8 a2 = *(const bf16x8*)&O[lane16 * 264 + k0 + quad * 8];
        #pragma unroll
        for (int j = 0; j < 2; ++j) {
            int ct = 2 * w + j;
            bf16x8 b2 = *(const bf16x8*)&W2bT[(ct * 16 + lane16) * 256 + k0 + quad * 8];
            acc2[j] = __builtin_amdgcn_mfma_f32_16x16x32_bf16(a2, b2, acc2[j], 0, 0, 0);
        }
    }
    float ps[4] = {0.f, 0.f, 0.f, 0.f}, pd[4] = {0.f, 0.f, 0.f, 0.f};
    #pragma unroll
    for (int j = 0; j < 2; ++j) {
        int col = (2 * w + j) * 16 + lane16;
        float a_s = as2[col], a_d = ad2[col];
        #pragma unroll
        for (int r2 = 0; r2 < 4; ++r2) {
            ps[r2] += acc2[j][r2] * a_s;
            pd[r2] += acc2[j][r2] * a_d;
            h2b[(n0 + quad * 4 + r2) * 128 + col] = f2bf(acc2[j][r2]);
        }
    }
    #pragma unroll
    for (int off = 1; off <= 8; off <<= 1)
        #pragma unroll
        for (int r2 = 0; r2 < 4; ++r2) {
            ps[r2] += __shfl_xor(ps[r2], off);
            pd[r2] += __shfl_xor(pd[r2], off);
        }
    if (lane16 == 0) {
        #pragma unroll
        for (int r2 = 0; r2 < 4; ++r2) {
            P[w][0][quad * 4 + r2] = ps[r2];
            P[w][1][quad * 4 + r2] = pd[r2];
        }
    }
    __syncthreads();
    if (threadIdx.x < 32) {
        int m = threadIdx.x & 15, hd = threadIdx.x >> 4;
        s2[(n0 + m) * 4 + hd]     = P[2 * hd][0][m] + P[2 * hd + 1][0][m];
        s2[(n0 + m) * 4 + 2 + hd] = P[2 * hd][1][m] + P[2 * hd + 1][1][m];
    }
}

// -------- layer-2 aggregate: wave-per-node, no-max softmax, 4x unrolled ----

__global__ __launch_bounds__(256) void k_agg2_csr(const int* __restrict__ rowptr,
        const int* __restrict__ eidx, const float* __restrict__ s2,
        const short* __restrict__ h2b, const float* __restrict__ b2,
        const float* __restrict__ Wfc, const float* __restrict__ bfc,
        float* __restrict__ out) {
    int wave = threadIdx.x >> 6;
    int l = threadIdx.x & 63;
    int n = blockIdx.x * 4 + wave;           // grid 12500 -> exact
    int beg = rowptr[n];
    int deg = rowptr[n + 1] - beg;
    int h = l >> 5;
    float sd = s2[n * 4 + 2 + h];
    float2 acc = make_float2(0.f, 0.f);
    float z = 0.f;
    int i = 0;
    for (; i + 4 <= deg; i += 4) {
        int a0 = eidx[beg + i], a1 = eidx[beg + i + 1];
        int a2 = eidx[beg + i + 2], a3 = eidx[beg + i + 3];
        float e0 = __expf(leaky(s2[a0 * 4 + h] + sd));
        float e1 = __expf(leaky(s2[a1 * 4 + h] + sd));
        float e2 = __expf(leaky(s2[a2 * 4 + h] + sd));
        float e3 = __expf(leaky(s2[a3 * 4 + h] + sd));
        unsigned v0 = *(const unsigned*)(h2b + a0 * 128 + l * 2);
        unsigned v1 = *(const unsigned*)(h2b + a1 * 128 + l * 2);
        unsigned v2 = *(const unsigned*)(h2b + a2 * 128 + l * 2);
        unsigned v3 = *(const unsigned*)(h2b + a3 * 128 + l * 2);
        z += e0 + e1 + e2 + e3;
        acc.x += e0 * bflo(v0) + e1 * bflo(v1) + e2 * bflo(v2) + e3 * bflo(v3);
        acc.y += e0 * bfhi(v0) + e1 * bfhi(v1) + e2 * bfhi(v2) + e3 * bfhi(v3);
    }
    for (; i < deg; ++i) {
        int a0 = eidx[beg + i];
        float e0 = __expf(leaky(s2[a0 * 4 + h] + sd));
        unsigned v0 = *(const unsigned*)(h2b + a0 * 128 + l * 2);
        z += e0;
        acc.x += e0 * bflo(v0); acc.y += e0 * bfhi(v0);
    }
    float inv = 1.f / (z + EPS);
    float v0 = acc.x * inv + b2[l * 2];
    float v1 = acc.y * inv + b2[l * 2 + 1];
    v0 = v0 > 0.f ? v0 : __expf(v0) - 1.f;
    v1 = v1 > 0.f ? v1 : __expf(v1) - 1.f;
    float p = v0 * Wfc[l * 2] + v1 * Wfc[l * 2 + 1];
    #pragma unroll
    for (int off = 1; off <= 32; off <<= 1) p += __shfl_xor(p, off);
    if (l == 0) out[n] = 1.f / (1.f + __expf(-(p + bfc[0])));
}

extern "C" void kernel_launch(void* const* d_in, const int* in_sizes, int n_in,
                              void* d_out, int out_size, void* d_ws, size_t ws_size,
                              hipStream_t stream) {
    const float* x   = (const float*)d_in[0];
    const int*   ei  = (const int*)d_in[1];
    const float* W1  = (const float*)d_in[2];
    const float* as1 = (const float*)d_in[3];
    const float* ad1 = (const float*)d_in[4];
    const float* b1  = (const float*)d_in[5];
    const float* W2  = (const float*)d_in[6];
    const float* as2 = (const float*)d_in[7];
    const float* ad2 = (const float*)d_in[8];
    const float* b2  = (const float*)d_in[9];
    const float* Wfc = (const float*)d_in[10];
    const float* bfc = (const float*)d_in[11];
    float* out = (float*)d_out;

    float* f = (float*)d_ws;
    short* h2b   = (short*)f;                    // N*128 bf16
    float* s1    = f + 3200000;                  // N*8
    float* s2    = f + 3600000;                  // N*4
    float* wsv   = f + 3800000;                  // 27*8
    int*   rowptr= (int*)(f + 3810000);          // N+1
    int*   cursor= (int*)(f + 3870000);          // N
    int*   deg   = (int*)(f + 3930000);          // N
    int*   eidx  = (int*)(f + 3990000);          // E_TOT
    int*   bsum  = (int*)(f + 4340000);          // 256
    int*   bofs  = (int*)(f + 4341000);          // 256
    short* W1b   = (short*)(f + 4342000);        // 4*64*32 bf16
    short* W2bT  = (short*)(f + 4350000);        // 128*256 bf16

    // CSR build
    hipMemsetAsync(deg, 0, (size_t)N_NODES * 4, stream);
    k_hist<<<(E_TOT + 255) / 256, 256, 0, stream>>>(ei, deg);
    k_blocksum<<<SCAN_BLOCKS, 256, 0, stream>>>(deg, bsum);
    k_scanb<<<1, 256, 0, stream>>>(bsum, bofs);
    k_rowptr<<<SCAN_BLOCKS, 256, 0, stream>>>(deg, bofs, rowptr, cursor);
    k_scatter<<<(E_TOT + 255) / 256, 256, 0, stream>>>(ei, cursor, eidx);

    // weight prep + s1
    k_prep<<<128, 256, 0, stream>>>(W1, as1, ad1, W2, wsv, W1b, W2bT);
    k_s1<<<(N_NODES * 8 + 255) / 256, 256, 0, stream>>>(x, wsv, s1);

    // fused: layer-1 aggregation (x-space) + expand + GEMM2 -> h2b, s2
    k_fused1<<<3125, 256, 0, stream>>>(rowptr, eidx, x, s1, W1b, W2bT, b1,
                                       as2, ad2, h2b, s2);

    // layer-2 aggregation + final FC + sigmoid
    k_agg2_csr<<<12500, 256, 0, stream>>>(rowptr, eidx, s2, h2b, b2, Wfc, bfc, out);
}

// Round 11
// 206.888 us; speedup vs baseline: 4.7904x; 1.0381x over previous
//
#include <hip/hip_runtime.h>
#include <math.h>

#define N_NODES 50000
#define E_EDGES 300000
#define E_TOT   350000   // E + N self-loops
#define NEG 0.2f
#define EPS 1e-16f
#define SCAN_BLOCKS 196  // 196*256 = 50176 >= 50000

typedef __attribute__((ext_vector_type(8))) short bf16x8;
typedef __attribute__((ext_vector_type(4))) float f32x4;

__device__ __forceinline__ float leaky(float x) { return x > 0.f ? x : NEG * x; }
// fp32 -> bf16 (RNE, finite inputs)
__device__ __forceinline__ short f2bf(float v) {
    unsigned u = __float_as_uint(v);
    u += 0x7fffu + ((u >> 16) & 1u);
    return (short)(u >> 16);
}
__device__ __forceinline__ float bflo(unsigned u) { return __uint_as_float(u << 16); }
__device__ __forceinline__ float bfhi(unsigned u) { return __uint_as_float(u & 0xffff0000u); }

// ---------------- CSR construction ----------------

__global__ __launch_bounds__(256) void k_hist(const int* __restrict__ ei,
        int* __restrict__ deg) {
    int e = blockIdx.x * 256 + threadIdx.x;
    if (e >= E_TOT) return;
    int d = (e < E_EDGES) ? ei[E_EDGES + e] : (e - E_EDGES);
    atomicAdd(&deg[d], 1);
}

__global__ __launch_bounds__(256) void k_blocksum(const int* __restrict__ deg,
        int* __restrict__ bsum) {
    int t = threadIdx.x;
    int idx = blockIdx.x * 256 + t;
    int v = (idx < N_NODES) ? deg[idx] : 0;
    #pragma unroll
    for (int off = 32; off > 0; off >>= 1) v += __shfl_down(v, off);
    __shared__ int ws[4];
    if ((t & 63) == 0) ws[t >> 6] = v;
    __syncthreads();
    if (t == 0) bsum[blockIdx.x] = ws[0] + ws[1] + ws[2] + ws[3];
}

__global__ __launch_bounds__(256) void k_scanb(const int* __restrict__ bsum,
        int* __restrict__ bofs) {
    __shared__ int sh[256];
    int t = threadIdx.x;
    sh[t] = (t < SCAN_BLOCKS) ? bsum[t] : 0;
    __syncthreads();
    for (int s = 1; s < 256; s <<= 1) {
        int v = (t >= s) ? sh[t - s] : 0;
        __syncthreads();
        sh[t] += v;
        __syncthreads();
    }
    bofs[t] = (t == 0) ? 0 : sh[t - 1];
}

__global__ __launch_bounds__(256) void k_rowptr(const int* __restrict__ deg,
        const int* __restrict__ bofs, int* __restrict__ rowptr,
        int* __restrict__ cursor) {
    __shared__ int sh[256];
    int t = threadIdx.x;
    int idx = blockIdx.x * 256 + t;
    int v = (idx < N_NODES) ? deg[idx] : 0;
    sh[t] = v;
    __syncthreads();
    for (int s = 1; s < 256; s <<= 1) {
        int u = (t >= s) ? sh[t - s] : 0;
        __syncthreads();
        sh[t] += u;
        __syncthreads();
    }
    int excl = sh[t] - v + bofs[blockIdx.x];
    if (idx < N_NODES) { rowptr[idx] = excl; cursor[idx] = excl; }
    if (idx == N_NODES) rowptr[N_NODES] = E_TOT;
}

__global__ __launch_bounds__(256) void k_scatter(const int* __restrict__ ei,
        int* __restrict__ cursor, int* __restrict__ eidx) {
    int e = blockIdx.x * 256 + threadIdx.x;
    if (e >= E_TOT) return;
    int s = (e < E_EDGES) ? ei[e] : (e - E_EDGES);
    int d = (e < E_EDGES) ? ei[E_EDGES + e] : (e - E_EDGES);
    int pos = atomicAdd(&cursor[d], 1);
    eidx[pos] = s;
}

// ---------------- prep: wsv = W1·a vectors, W1b (padded B^T), W2bT ----------

__global__ __launch_bounds__(256) void k_prep(const float* __restrict__ W1,
        const float* __restrict__ as1, const float* __restrict__ ad1,
        const float* __restrict__ W2, float* __restrict__ wsv,
        short* __restrict__ W1b, short* __restrict__ W2bT) {
    int t = blockIdx.x * 256 + threadIdx.x;      // grid 128 -> 32768 threads
    // W2bT[col][k] = W2[k][col]
    {
        int col = t >> 8, k = t & 255;
        W2bT[t] = f2bf(W2[k * 128 + col]);
    }
    // W1b[h][col][k] = W1[k][h*64+col], k padded 27->32
    if (t < 8192) {
        int h = t >> 11, col = (t >> 5) & 63, k = t & 31;
        W1b[t] = f2bf(k < 27 ? W1[k * 256 + h * 64 + col] : 0.f);
    }
    // wsv[k][j]: j<4 -> sum_d W1[k][j*64+d]*as1[j*64+d]; j>=4 -> ad1
    if (t < 216) {
        int k = t >> 3, j = t & 7;
        const float* av = (j < 4) ? (as1 + j * 64) : (ad1 + (j - 4) * 64);
        const float* wr = W1 + k * 256 + ((j & 3) * 64);
        float s = 0.f;
        for (int d = 0; d < 64; ++d) s += wr[d] * av[d];
        wsv[k * 8 + j] = s;
    }
}

// s1[n][0..3]=src half-scores, [4..7]=dst — direct from x via wsv (27->8 GEMV)
__global__ __launch_bounds__(256) void k_s1(const float* __restrict__ x,
        const float* __restrict__ wsv, float* __restrict__ s1) {
    int idx = blockIdx.x * 256 + threadIdx.x;    // grid 1563
    if (idx >= N_NODES * 8) return;
    int n = idx >> 3, j = idx & 7;
    float s = 0.f;
    #pragma unroll
    for (int k = 0; k < 27; ++k) s += x[n * 27 + k] * wsv[k * 8 + j];
    s1[idx] = s;
}

// ---------------- fused layer-1 agg (x-space) + expand + GEMM2 ----------------
// Block = 16 nodes. Phase A: waves aggregate xagg[h][m][c] (fp32->bf16, LDS),
//   edge loop 4x unrolled (independent gathers in flight).
// Phase B: wave w = head w expands out1'[16x64] via 4 MFMAs -> elu -> LDS O.
// Phase C: wave w computes h2 col-tiles {2w,2w+1} (K=256, 16 MFMAs) + s2.
__global__ __launch_bounds__(256) void k_fused1(const int* __restrict__ rowptr,
        const int* __restrict__ eidx, const float* __restrict__ x,
        const float* __restrict__ s1, const short* __restrict__ W1b,
        const short* __restrict__ W2bT, const float* __restrict__ b1,
        const float* __restrict__ as2, const float* __restrict__ ad2,
        short* __restrict__ h2b, float* __restrict__ s2) {
    __shared__ short LDSx[4 * 16 * 32];          // [head][m][k] bf16
    __shared__ short O[16 * 264];                // out1' [m][col], padded stride
    __shared__ float P[4][2][16];                // s2 partials [wave][ps/pd][m]
    int w = threadIdx.x >> 6, l = threadIdx.x & 63;
    int n0 = blockIdx.x * 16;                    // grid 3125 -> 50000 exact
    int h5 = l >> 5, c = l & 31;                 // half-wave, channel slot
    f32x4 z4 = {0.f, 0.f, 0.f, 0.f};

    // Phase A: each wave aggregates 4 nodes (2 rounds x 2 half-waves)
    for (int r = 0; r < 2; ++r) {
        int m = w * 4 + r * 2 + h5;
        int n = n0 + m;
        int beg = rowptr[n];
        int deg = rowptr[n + 1] - beg;
        int degmax = max(deg, __shfl_xor(deg, 32));
        float4 sdv = *(const float4*)(s1 + n * 8 + 4);
        float a0 = 0.f, a1 = 0.f, a2 = 0.f, a3 = 0.f;
        float z0 = 0.f, z1 = 0.f, z2 = 0.f, z3 = 0.f;
        int i = 0;
        for (; i + 4 <= degmax; i += 4) {
            bool c0 = (i + 0) < deg, c1 = (i + 1) < deg;
            bool c2 = (i + 2) < deg, c3 = (i + 3) < deg;
            int s0 = c0 ? eidx[beg + i + 0] : n;
            int s1i = c1 ? eidx[beg + i + 1] : n;
            int s2i = c2 ? eidx[beg + i + 2] : n;
            int s3 = c3 ? eidx[beg + i + 3] : n;
            float4 sv0 = *(const float4*)(s1 + s0 * 8);
            float4 sv1 = *(const float4*)(s1 + s1i * 8);
            float4 sv2 = *(const float4*)(s1 + s2i * 8);
            float4 sv3 = *(const float4*)(s1 + s3 * 8);
            float xv0 = (c0 && c < 27) ? x[s0 * 27 + c] : 0.f;
            float xv1 = (c1 && c < 27) ? x[s1i * 27 + c] : 0.f;
            float xv2 = (c2 && c < 27) ? x[s2i * 27 + c] : 0.f;
            float xv3 = (c3 && c < 27) ? x[s3 * 27 + c] : 0.f;
            float g0 = c0 ? 1.f : 0.f, g1 = c1 ? 1.f : 0.f;
            float g2 = c2 ? 1.f : 0.f, g3 = c3 ? 1.f : 0.f;
            float e00 = g0 * __expf(leaky(sv0.x + sdv.x));
            float e01 = g0 * __expf(leaky(sv0.y + sdv.y));
            float e02 = g0 * __expf(leaky(sv0.z + sdv.z));
            float e03 = g0 * __expf(leaky(sv0.w + sdv.w));
            float e10 = g1 * __expf(leaky(sv1.x + sdv.x));
            float e11 = g1 * __expf(leaky(sv1.y + sdv.y));
            float e12 = g1 * __expf(leaky(sv1.z + sdv.z));
            float e13 = g1 * __expf(leaky(sv1.w + sdv.w));
            float e20 = g2 * __expf(leaky(sv2.x + sdv.x));
            float e21 = g2 * __expf(leaky(sv2.y + sdv.y));
            float e22 = g2 * __expf(leaky(sv2.z + sdv.z));
            float e23 = g2 * __expf(leaky(sv2.w + sdv.w));
            float e30 = g3 * __expf(leaky(sv3.x + sdv.x));
            float e31 = g3 * __expf(leaky(sv3.y + sdv.y));
            float e32 = g3 * __expf(leaky(sv3.z + sdv.z));
            float e33 = g3 * __expf(leaky(sv3.w + sdv.w));
            z0 += e00 + e10 + e20 + e30;
            z1 += e01 + e11 + e21 + e31;
            z2 += e02 + e12 + e22 + e32;
            z3 += e03 + e13 + e23 + e33;
            a0 += e00 * xv0 + e10 * xv1 + e20 * xv2 + e30 * xv3;
            a1 += e01 * xv0 + e11 * xv1 + e21 * xv2 + e31 * xv3;
            a2 += e02 * xv0 + e12 * xv1 + e22 * xv2 + e32 * xv3;
            a3 += e03 * xv0 + e13 * xv1 + e23 * xv2 + e33 * xv3;
        }
        for (; i < degmax; ++i) {
            bool act = i < deg;
            int src = act ? eidx[beg + i] : n;
            float4 sv = *(const float4*)(s1 + src * 8);
            float g = act ? 1.f : 0.f;
            float e0 = g * __expf(leaky(sv.x + sdv.x));
            float e1 = g * __expf(leaky(sv.y + sdv.y));
            float e2 = g * __expf(leaky(sv.z + sdv.z));
            float e3 = g * __expf(leaky(sv.w + sdv.w));
            float xv = (act && c < 27) ? x[src * 27 + c] : 0.f;
            z0 += e0; z1 += e1; z2 += e2; z3 += e3;
            a0 += e0 * xv; a1 += e1 * xv; a2 += e2 * xv; a3 += e3 * xv;
        }
        float i0 = 1.f / (z0 + EPS), i1 = 1.f / (z1 + EPS);
        float i2 = 1.f / (z2 + EPS), i3 = 1.f / (z3 + EPS);
        LDSx[0 * 512 + m * 32 + c] = f2bf(a0 * i0);
        LDSx[1 * 512 + m * 32 + c] = f2bf(a1 * i1);
        LDSx[2 * 512 + m * 32 + c] = f2bf(a2 * i2);
        LDSx[3 * 512 + m * 32 + c] = f2bf(a3 * i3);
    }
    __syncthreads();

    int lane16 = l & 15, quad = l >> 4;
    // Phase B: expand head w: [16x32] @ [32x64] -> elu -> O
    {
        bf16x8 a = *(const bf16x8*)&LDSx[w * 512 + lane16 * 32 + quad * 8];
        f32x4 cacc[4];
        #pragma unroll
        for (int nt = 0; nt < 4; ++nt) {
            bf16x8 b = *(const bf16x8*)&W1b[w * 2048 + (nt * 16 + lane16) * 32 + quad * 8];
            cacc[nt] = __builtin_amdgcn_mfma_f32_16x16x32_bf16(a, b, z4, 0, 0, 0);
        }
        #pragma unroll
        for (int nt = 0; nt < 4; ++nt) {
            int col = w * 64 + nt * 16 + lane16;
            float bb = b1[col];
            #pragma unroll
            for (int r2 = 0; r2 < 4; ++r2) {
                float v = cacc[nt][r2] + bb;
                v = v > 0.f ? v : __expf(v) - 1.f;
                O[(quad * 4 + r2) * 264 + col] = f2bf(v);
            }
        }
    }
    __syncthreads();

    // Phase C: gemm2, wave w -> h2 col-tiles {2w, 2w+1}
    f32x4 acc2[2];
    acc2[0] = z4; acc2[1] = z4;
    for (int k0 = 0; k0 < 256; k0 += 32) {
        bf16x8 a2 = *(const bf16x8*)&O[lane16 * 264 + k0 + quad * 8];
        #pragma unroll
        for (int j = 0; j < 2; ++j) {
            int ct = 2 * w + j;
            bf16x8 b2 = *(const bf16x8*)&W2bT[(ct * 16 + lane16) * 256 + k0 + quad * 8];
            acc2[j] = __builtin_amdgcn_mfma_f32_16x16x32_bf16(a2, b2, acc2[j], 0, 0, 0);
        }
    }
    float ps[4] = {0.f, 0.f, 0.f, 0.f}, pd[4] = {0.f, 0.f, 0.f, 0.f};
    #pragma unroll
    for (int j = 0; j < 2; ++j) {
        int col = (2 * w + j) * 16 + lane16;
        float a_s = as2[col], a_d = ad2[col];
        #pragma unroll
        for (int r2 = 0; r2 < 4; ++r2) {
            ps[r2] += acc2[j][r2] * a_s;
            pd[r2] += acc2[j][r2] * a_d;
            h2b[(n0 + quad * 4 + r2) * 128 + col] = f2bf(acc2[j][r2]);
        }
    }
    #pragma unroll
    for (int off = 1; off <= 8; off <<= 1)
        #pragma unroll
        for (int r2 = 0; r2 < 4; ++r2) {
            ps[r2] += __shfl_xor(ps[r2], off);
            pd[r2] += __shfl_xor(pd[r2], off);
        }
    if (lane16 == 0) {
        #pragma unroll
        for (int r2 = 0; r2 < 4; ++r2) {
            P[w][0][quad * 4 + r2] = ps[r2];
            P[w][1][quad * 4 + r2] = pd[r2];
        }
    }
    __syncthreads();
    if (threadIdx.x < 32) {
        int m = threadIdx.x & 15, hd = threadIdx.x >> 4;
        s2[(n0 + m) * 4 + hd]     = P[2 * hd][0][m] + P[2 * hd + 1][0][m];
        s2[(n0 + m) * 4 + 2 + hd] = P[2 * hd][1][m] + P[2 * hd + 1][1][m];
    }
}

// -------- layer-2 aggregate: wave-per-node, no-max softmax, 4x unrolled ----

__global__ __launch_bounds__(256) void k_agg2_csr(const int* __restrict__ rowptr,
        const int* __restrict__ eidx, const float* __restrict__ s2,
        const short* __restrict__ h2b, const float* __restrict__ b2,
        const float* __restrict__ Wfc, const float* __restrict__ bfc,
        float* __restrict__ out) {
    int wave = threadIdx.x >> 6;
    int l = threadIdx.x & 63;
    int n = blockIdx.x * 4 + wave;           // grid 12500 -> exact
    int beg = rowptr[n];
    int deg = rowptr[n + 1] - beg;
    int h = l >> 5;
    float sd = s2[n * 4 + 2 + h];
    float2 acc = make_float2(0.f, 0.f);
    float z = 0.f;
    int i = 0;
    for (; i + 4 <= deg; i += 4) {
        int a0 = eidx[beg + i], a1 = eidx[beg + i + 1];
        int a2 = eidx[beg + i + 2], a3 = eidx[beg + i + 3];
        float e0 = __expf(leaky(s2[a0 * 4 + h] + sd));
        float e1 = __expf(leaky(s2[a1 * 4 + h] + sd));
        float e2 = __expf(leaky(s2[a2 * 4 + h] + sd));
        float e3 = __expf(leaky(s2[a3 * 4 + h] + sd));
        unsigned v0 = *(const unsigned*)(h2b + a0 * 128 + l * 2);
        unsigned v1 = *(const unsigned*)(h2b + a1 * 128 + l * 2);
        unsigned v2 = *(const unsigned*)(h2b + a2 * 128 + l * 2);
        unsigned v3 = *(const unsigned*)(h2b + a3 * 128 + l * 2);
        z += e0 + e1 + e2 + e3;
        acc.x += e0 * bflo(v0) + e1 * bflo(v1) + e2 * bflo(v2) + e3 * bflo(v3);
        acc.y += e0 * bfhi(v0) + e1 * bfhi(v1) + e2 * bfhi(v2) + e3 * bfhi(v3);
    }
    for (; i < deg; ++i) {
        int a0 = eidx[beg + i];
        float e0 = __expf(leaky(s2[a0 * 4 + h] + sd));
        unsigned v0 = *(const unsigned*)(h2b + a0 * 128 + l * 2);
        z += e0;
        acc.x += e0 * bflo(v0); acc.y += e0 * bfhi(v0);
    }
    float inv = 1.f / (z + EPS);
    float v0 = acc.x * inv + b2[l * 2];
    float v1 = acc.y * inv + b2[l * 2 + 1];
    v0 = v0 > 0.f ? v0 : __expf(v0) - 1.f;
    v1 = v1 > 0.f ? v1 : __expf(v1) - 1.f;
    float p = v0 * Wfc[l * 2] + v1 * Wfc[l * 2 + 1];
    #pragma unroll
    for (int off = 1; off <= 32; off <<= 1) p += __shfl_xor(p, off);
    if (l == 0) out[n] = 1.f / (1.f + __expf(-(p + bfc[0])));
}

extern "C" void kernel_launch(void* const* d_in, const int* in_sizes, int n_in,
                              void* d_out, int out_size, void* d_ws, size_t ws_size,
                              hipStream_t stream) {
    const float* x   = (const float*)d_in[0];
    const int*   ei  = (const int*)d_in[1];
    const float* W1  = (const float*)d_in[2];
    const float* as1 = (const float*)d_in[3];
    const float* ad1 = (const float*)d_in[4];
    const float* b1  = (const float*)d_in[5];
    const float* W2  = (const float*)d_in[6];
    const float* as2 = (const float*)d_in[7];
    const float* ad2 = (const float*)d_in[8];
    const float* b2  = (const float*)d_in[9];
    const float* Wfc = (const float*)d_in[10];
    const float* bfc = (const float*)d_in[11];
    float* out = (float*)d_out;

    float* f = (float*)d_ws;
    short* h2b   = (short*)f;                    // N*128 bf16
    float* s1    = f + 3200000;                  // N*8
    float* s2    = f + 3600000;                  // N*4
    float* wsv   = f + 3800000;                  // 27*8
    int*   rowptr= (int*)(f + 3810000);          // N+1
    int*   cursor= (int*)(f + 3870000);          // N
    int*   deg   = (int*)(f + 3930000);          // N
    int*   eidx  = (int*)(f + 3990000);          // E_TOT
    int*   bsum  = (int*)(f + 4340000);          // 256
    int*   bofs  = (int*)(f + 4341000);          // 256
    short* W1b   = (short*)(f + 4342000);        // 4*64*32 bf16
    short* W2bT  = (short*)(f + 4350000);        // 128*256 bf16

    // CSR build
    hipMemsetAsync(deg, 0, (size_t)N_NODES * 4, stream);
    k_hist<<<(E_TOT + 255) / 256, 256, 0, stream>>>(ei, deg);
    k_blocksum<<<SCAN_BLOCKS, 256, 0, stream>>>(deg, bsum);
    k_scanb<<<1, 256, 0, stream>>>(bsum, bofs);
    k_rowptr<<<SCAN_BLOCKS, 256, 0, stream>>>(deg, bofs, rowptr, cursor);
    k_scatter<<<(E_TOT + 255) / 256, 256, 0, stream>>>(ei, cursor, eidx);

    // weight prep + s1
    k_prep<<<128, 256, 0, stream>>>(W1, as1, ad1, W2, wsv, W1b, W2bT);
    k_s1<<<(N_NODES * 8 + 255) / 256, 256, 0, stream>>>(x, wsv, s1);

    // fused: layer-1 aggregation (x-space) + expand + GEMM2 -> h2b, s2
    k_fused1<<<3125, 256, 0, stream>>>(rowptr, eidx, x, s1, W1b, W2bT, b1,
                                       as2, ad2, h2b, s2);

    // layer-2 aggregation + final FC + sigmoid
    k_agg2_csr<<<12500, 256, 0, stream>>>(rowptr, eidx, s2, h2b, b2, Wfc, bfc, out);
}